// Round 1
// baseline (1016.425 us; speedup 1.0000x reference)
//
#include <hip/hip_runtime.h>
#include <math.h>

#define N_NODES 100000
#define N_EDGES 3200000
#define KSEL    800
#define MAXD    192

// output layout (floats)
#define OUT_H     0
#define OUT_SCORE 700000
#define OUT_JACC  13500000
#define OUT_TOP   13600000

// ws layout (bytes)
#define OFF_DEG   0         // int[100000]
#define OFF_CUR   400000    // int[100000]
#define OFF_HIST  800000    // uint[65536]
#define OFF_SCAL  1062144   // int[64]
#define ZERO_BYTES 1062400  // memset region [0, here)
#define OFF_OFFS  1062400   // int[100001] (+pad)
#define OFF_KEYS  1462416   // u64[100000]
#define OFF_CAND  2262416   // u64[4096]
#define OFF_BINS  2295184   // int[3200000]

__global__ void k_deg(const int* __restrict__ dst, int* __restrict__ deg) {
    int i = blockIdx.x * 256 + threadIdx.x;
    if (i < N_EDGES) atomicAdd(&deg[dst[i]], 1);
}

__global__ __launch_bounds__(1024) void k_scan(const int* __restrict__ deg,
                                               int* __restrict__ offs) {
    __shared__ int part[1024];
    int t = threadIdx.x;
    const int CH = 98;
    int c0 = t * CH;
    int c1 = c0 + CH; if (c1 > N_NODES) c1 = N_NODES;
    int s = 0;
    for (int i = c0; i < c1; ++i) s += deg[i];
    part[t] = s;
    __syncthreads();
    for (int off = 1; off < 1024; off <<= 1) {
        int v = (t >= off) ? part[t - off] : 0;
        __syncthreads();
        part[t] += v;
        __syncthreads();
    }
    int run = part[t] - s;   // exclusive base
    for (int i = c0; i < c1; ++i) { offs[i] = run; run += deg[i]; }
}

__global__ void k_fill(const int* __restrict__ dst, const int* __restrict__ offs,
                       int* __restrict__ cur, int* __restrict__ bins) {
    int i = blockIdx.x * 256 + threadIdx.x;
    if (i < N_EDGES) {
        int d = dst[i];
        int p = offs[d] + atomicAdd(&cur[d], 1);
        bins[p] = i;
    }
}

// per-node: sequential fp32 sum in ORIGINAL edge order (matches np/XLA scatter-add),
// max, jaccard, sortable key, 16-bit-bucket histogram
__global__ void k_node(const float* __restrict__ e, const int* __restrict__ deg,
                       const int* __restrict__ offs, const int* __restrict__ bins,
                       float* __restrict__ out_jacc,
                       unsigned long long* __restrict__ keys,
                       unsigned int* __restrict__ hist) {
    int n = blockIdx.x * 256 + threadIdx.x;
    if (n >= N_NODES) return;
    int d = deg[n];
    float jac;
    if (d == 0) {
        jac = -INFINITY;
    } else {
        int st = offs[n];
        float sum = 0.f, mx = -INFINITY;
        if (d <= MAXD) {
            int loc[MAXD];
            for (int i = 0; i < d; ++i) loc[i] = bins[st + i];
            // insertion sort ascending (restore original edge order)
            for (int i = 1; i < d; ++i) {
                int v = loc[i]; int j = i - 1;
                while (j >= 0 && loc[j] > v) { loc[j + 1] = loc[j]; --j; }
                loc[j + 1] = v;
            }
            for (int i = 0; i < d; ++i) {
                float v = e[loc[i]];
                sum += v;
                mx = fmaxf(mx, v);
            }
        } else {
            // pathological-degree fallback: O(d^2) in-order selection
            int last = -1;
            for (int r = 0; r < d; ++r) {
                int best = 0x7fffffff;
                for (int i = 0; i < d; ++i) {
                    int v = bins[st + i];
                    if (v > last && v < best) best = v;
                }
                float vv = e[best];
                sum += vv;
                mx = fmaxf(mx, vv);
                last = best;
            }
        }
        float dd = (float)d;                   // deg_safe (d>=1 here)
        float mean = sum / dd;                 // IEEE f32 divide
        float lg = (float)log((double)dd);     // correctly-rounded f32 log
        jac = (mx - mean) - lg;                // match ref associativity
    }
    out_jacc[n] = jac;
    unsigned int s = __float_as_uint(jac);
    unsigned int asc = (s & 0x80000000u) ? ~s : (s | 0x80000000u); // ascending-monotone
    unsigned int desc = ~asc;                                      // descending-monotone
    unsigned long long key = ((unsigned long long)desc << 32) | (unsigned int)n;
    keys[n] = key;
    atomicAdd(&hist[desc >> 16], 1u);
}

__global__ __launch_bounds__(1024) void k_cutoff(const unsigned int* __restrict__ hist,
                                                 int* __restrict__ scal) {
    __shared__ int part[1024];
    int t = threadIdx.x;
    int s = 0;
    for (int b = t * 64; b < t * 64 + 64; ++b) s += (int)hist[b];
    part[t] = s;
    __syncthreads();
    for (int off = 1; off < 1024; off <<= 1) {
        int v = (t >= off) ? part[t - off] : 0;
        __syncthreads();
        part[t] += v;
        __syncthreads();
    }
    int inc = part[t];
    int base = inc - s;
    if (base < KSEL && inc >= KSEL) {   // crossing is in my chunk (exactly one thread)
        int run = base;
        for (int b = t * 64; b < t * 64 + 64; ++b) {
            run += (int)hist[b];
            if (run >= KSEL) { scal[0] = b; break; }
        }
    }
}

__global__ void k_collect(const unsigned long long* __restrict__ keys,
                          const int* __restrict__ scal,
                          unsigned long long* __restrict__ cand,
                          int* __restrict__ cnt) {
    int n = blockIdx.x * 256 + threadIdx.x;
    if (n >= N_NODES) return;
    unsigned int cb = (unsigned int)scal[0];
    unsigned long long k = keys[n];
    if ((unsigned int)(k >> 48) <= cb) {
        int p = atomicAdd(cnt, 1);
        if (p < 4096) cand[p] = k;
    }
}

__global__ __launch_bounds__(1024) void k_sort(const unsigned long long* __restrict__ cand,
                                               const int* __restrict__ cnt,
                                               float* __restrict__ out_top) {
    __shared__ unsigned long long sk[4096];
    int t = threadIdx.x;
    int cc = *cnt; if (cc > 4096) cc = 4096;
    for (int i = t; i < 4096; i += 1024)
        sk[i] = (i < cc) ? cand[i] : 0xFFFFFFFFFFFFFFFFULL;
    __syncthreads();
    for (int k = 2; k <= 4096; k <<= 1) {
        for (int j = k >> 1; j > 0; j >>= 1) {
            for (int i = t; i < 4096; i += 1024) {
                int ixj = i ^ j;
                if (ixj > i) {
                    unsigned long long a = sk[i], b = sk[ixj];
                    bool up = ((i & k) == 0);
                    if ((a > b) == up) { sk[i] = b; sk[ixj] = a; }
                }
            }
            __syncthreads();
        }
    }
    for (int r = t; r < KSEL; r += 1024)
        out_top[r] = (float)(unsigned int)(sk[r] & 0xFFFFFFFFULL);
}

__global__ void k_score(const int* __restrict__ dst, const int* __restrict__ deg,
                        float4* __restrict__ out_s) {
    int i = blockIdx.x * 256 + threadIdx.x;
    if (i < N_EDGES) {
        int d = deg[dst[i]];
        if (d < 1) d = 1;
        float v = 1.0f / (float)d;
        out_s[i] = make_float4(v, v, v, v);
    }
}

// fused: h = emb[tok] + (pos @ lapW + lapb); MLPReadout (128->64->32->7)
// one wave per node, 4 nodes per block; weights staged in LDS
__global__ __launch_bounds__(256) void k_mlp(
    const int* __restrict__ tok, const float* __restrict__ pos,
    const float* __restrict__ emb, const float* __restrict__ lapW,
    const float* __restrict__ lapb,
    const float* __restrict__ W0, const float* __restrict__ b0,
    const float* __restrict__ W1, const float* __restrict__ b1,
    const float* __restrict__ W2, const float* __restrict__ b2,
    float* __restrict__ out) {
    __shared__ float sW0[128 * 64];
    __shared__ float sW1[64 * 32];
    __shared__ float sW2[32 * 7];
    __shared__ float sLW[8 * 128];
    __shared__ float sLb[128];
    __shared__ float sb0[64], sb1[32], sb2[7];
    __shared__ float hb[4][128];
    __shared__ float x1[4][64];
    __shared__ float x2[4][32];
    int t = threadIdx.x;
    for (int i = t; i < 128 * 64; i += 256) sW0[i] = W0[i];
    for (int i = t; i < 64 * 32; i += 256) sW1[i] = W1[i];
    for (int i = t; i < 32 * 7; i += 256) sW2[i] = W2[i];
    for (int i = t; i < 8 * 128; i += 256) sLW[i] = lapW[i];
    if (t < 128) sLb[t] = lapb[t];
    if (t < 64) sb0[t] = b0[t];
    if (t < 32) sb1[t] = b1[t];
    if (t < 7) sb2[t] = b2[t];
    __syncthreads();

    int w = t >> 6, l = t & 63;
    int node = blockIdx.x * 4 + w;   // grid sized so node < N_NODES always

    int tk = tok[node];
    float p[8];
#pragma unroll
    for (int j = 0; j < 8; ++j) p[j] = pos[node * 8 + j];
#pragma unroll
    for (int c0 = 0; c0 < 128; c0 += 64) {
        int c = c0 + l;
        float acc = sLb[c];
#pragma unroll
        for (int j = 0; j < 8; ++j) acc += p[j] * sLW[j * 128 + c];
        hb[w][c] = emb[tk * 128 + c] + acc;
    }
    __syncthreads();

    float a1 = sb0[l];
    for (int k = 0; k < 128; ++k) a1 += hb[w][k] * sW0[k * 64 + l];
    x1[w][l] = fmaxf(a1, 0.f);
    __syncthreads();

    if (l < 32) {
        float a2 = sb1[l];
        for (int k = 0; k < 64; ++k) a2 += x1[w][k] * sW1[k * 32 + l];
        x2[w][l] = fmaxf(a2, 0.f);
    }
    __syncthreads();

    if (l < 7) {
        float a3 = sb2[l];
        for (int k = 0; k < 32; ++k) a3 += x2[w][k] * sW2[k * 7 + l];
        out[node * 7 + l] = a3;
    }
}

extern "C" void kernel_launch(void* const* d_in, const int* in_sizes, int n_in,
                              void* d_out, int out_size, void* d_ws, size_t ws_size,
                              hipStream_t stream) {
    const int*   h_tokens = (const int*)d_in[0];
    const int*   src      = (const int*)d_in[1];  (void)src;
    const int*   dst      = (const int*)d_in[2];
    const float* e        = (const float*)d_in[3];
    const float* pos      = (const float*)d_in[4];
    const float* emb      = (const float*)d_in[5];
    const float* lapW     = (const float*)d_in[6];
    const float* lapb     = (const float*)d_in[7];
    const float* W0 = (const float*)d_in[8];
    const float* b0 = (const float*)d_in[9];
    const float* W1 = (const float*)d_in[10];
    const float* b1 = (const float*)d_in[11];
    const float* W2 = (const float*)d_in[12];
    const float* b2 = (const float*)d_in[13];
    float* out = (float*)d_out;

    char* ws = (char*)d_ws;
    int* deg  = (int*)(ws + OFF_DEG);
    int* cur  = (int*)(ws + OFF_CUR);
    unsigned int* hist = (unsigned int*)(ws + OFF_HIST);
    int* scal = (int*)(ws + OFF_SCAL);  // [0]=cutoff bucket, [1]=candidate count
    int* offs = (int*)(ws + OFF_OFFS);
    unsigned long long* keys = (unsigned long long*)(ws + OFF_KEYS);
    unsigned long long* cand = (unsigned long long*)(ws + OFF_CAND);
    int* bins = (int*)(ws + OFF_BINS);

    hipMemsetAsync(d_ws, 0, ZERO_BYTES, stream);

    k_deg<<<12500, 256, 0, stream>>>(dst, deg);
    k_scan<<<1, 1024, 0, stream>>>(deg, offs);
    k_fill<<<12500, 256, 0, stream>>>(dst, offs, cur, bins);
    k_node<<<391, 256, 0, stream>>>(e, deg, offs, bins,
                                    out + OUT_JACC, keys, hist);
    k_cutoff<<<1, 1024, 0, stream>>>(hist, scal);
    k_collect<<<391, 256, 0, stream>>>(keys, scal, cand, scal + 1);
    k_sort<<<1, 1024, 0, stream>>>(cand, scal + 1, out + OUT_TOP);
    k_score<<<12500, 256, 0, stream>>>(dst, deg, (float4*)(out + OUT_SCORE));
    k_mlp<<<25000, 256, 0, stream>>>(h_tokens, pos, emb, lapW, lapb,
                                     W0, b0, W1, b1, W2, b2, out);
}

// Round 2
// 810.070 us; speedup vs baseline: 1.2547x; 1.2547x over previous
//
#include <hip/hip_runtime.h>
#include <math.h>

#define N_NODES 100000
#define N_EDGES 3200000
#define KSEL    800
#define CANDCAP 8192
#define SLOTS   256

// output layout (float offsets)
#define OUT_H     0
#define OUT_SCORE 700000
#define OUT_JACC  13500000
#define OUT_TOP   13600000

// ws layout (byte offsets)
#define OFF_STAT     0          // Stat[100000] = 1,600,000 B
#define OFF_HIST     1600000    // uint[65536]  = 262,144 B
#define OFF_CCUR     1862144    // int[8192]    = 32,768 B
#define OFF_SCAL     1894912    // int[64]      (scal[0]=cutoff bucket, scal[1]=cand count)
#define ZERO_END     1895168    // memset-0 region [0, here)
#define OFF_CANDID   1895168    // int[100000]  (memset 0xFF -> -1)
#define OFF_RCP      2295168    // float[100000]
#define OFF_KEYS     2695168    // u64[100000]
#define OFF_CANDNODE 3495168    // int[8192]
#define OFF_CANDKEY  3527936    // u64[8192]
#define OFF_CEDGE    3593472    // int[8192*256] = 8,388,608 B -> ends 11,982,080

struct Stat { unsigned int deg; float sum; unsigned int mx; unsigned int pad; };

// one pass over edges: deg count, approx fp32 sum, exact bitwise max (e >= 0)
__global__ void k_stats(const int* __restrict__ dst, const float* __restrict__ e,
                        Stat* __restrict__ stat) {
    int i = blockIdx.x * 256 + threadIdx.x;
    if (i < N_EDGES) {
        int d = dst[i];
        float v = e[i];
        Stat* s = stat + d;
        atomicAdd(&s->deg, 1u);
        atomicAdd(&s->sum, v);
        atomicMax(&s->mx, __float_as_uint(v));   // e in [0,1): uint-monotone
    }
}

// per node: approx jaccard, rcp for score, sortable key, 16-bit bucket histogram
__global__ void k_jacc(const Stat* __restrict__ stat,
                       float* __restrict__ out_jacc, float* __restrict__ rcp,
                       unsigned long long* __restrict__ keys,
                       unsigned int* __restrict__ hist) {
    int n = blockIdx.x * 256 + threadIdx.x;
    if (n >= N_NODES) return;
    int d = (int)stat[n].deg;
    float jac, r;
    if (d == 0) {
        jac = -INFINITY;
        r = 1.0f;
    } else {
        float dd = (float)d;
        r = 1.0f / dd;
        float mean = stat[n].sum / dd;
        float lg = (float)log((double)dd);
        float mx = __uint_as_float(stat[n].mx);
        jac = (mx - mean) - lg;
    }
    out_jacc[n] = jac;
    rcp[n] = r;
    unsigned int s = __float_as_uint(jac);
    unsigned int asc = (s & 0x80000000u) ? ~s : (s | 0x80000000u);
    unsigned int desc = ~asc;                     // descending-monotone
    keys[n] = ((unsigned long long)desc << 32) | (unsigned int)n;
    atomicAdd(&hist[desc >> 16], 1u);
}

__global__ __launch_bounds__(1024) void k_cutoff(const unsigned int* __restrict__ hist,
                                                 int* __restrict__ scal) {
    __shared__ int part[1024];
    int t = threadIdx.x;
    int s = 0;
    for (int b = t * 64; b < t * 64 + 64; ++b) s += (int)hist[b];
    part[t] = s;
    __syncthreads();
    for (int off = 1; off < 1024; off <<= 1) {
        int v = (t >= off) ? part[t - off] : 0;
        __syncthreads();
        part[t] += v;
        __syncthreads();
    }
    int inc = part[t];
    int base = inc - s;
    if (base < KSEL && inc >= KSEL) {   // crossing bucket is in my chunk
        int run = base;
        for (int b = t * 64; b < t * 64 + 64; ++b) {
            run += (int)hist[b];
            if (run >= KSEL) {
                int cb = b + 1;                    // +1 bucket safety margin
                if (cb > 65535) cb = 65535;
                scal[0] = cb;
                break;
            }
        }
    }
}

__global__ void k_collect(const unsigned long long* __restrict__ keys,
                          int* __restrict__ scal,
                          int* __restrict__ candid, int* __restrict__ candNode) {
    int n = blockIdx.x * 256 + threadIdx.x;
    if (n >= N_NODES) return;
    unsigned int cb = (unsigned int)scal[0];
    if ((unsigned int)(keys[n] >> 48) <= cb) {
        int cid = atomicAdd(&scal[1], 1);
        if (cid < CANDCAP) {
            candid[n] = cid;
            candNode[cid] = n;
        }
    }
}

// fused: write score (1/deg broadcast x4) + append candidate edges
__global__ void k_gather_score(const int* __restrict__ dst,
                               const float* __restrict__ rcp,
                               const int* __restrict__ candid,
                               int* __restrict__ ccur, int* __restrict__ cedge,
                               float4* __restrict__ out_s) {
    int i = blockIdx.x * 256 + threadIdx.x;
    if (i < N_EDGES) {
        int d = dst[i];
        float r = rcp[d];
        out_s[i] = make_float4(r, r, r, r);
        int cid = candid[d];
        if (cid >= 0) {
            int p = atomicAdd(&ccur[cid], 1);
            if (p < SLOTS) cedge[cid * SLOTS + p] = i;
        }
    }
}

// exact sequential-order fp32 sum for candidates only (wave per candidate)
__global__ __launch_bounds__(256) void k_exact(
    const int* __restrict__ dst, const float* __restrict__ e,
    const Stat* __restrict__ stat, const int* __restrict__ candNode,
    const int* __restrict__ cedge, const int* __restrict__ scal,
    float* __restrict__ out_jacc, unsigned long long* __restrict__ candKey) {
    int w = threadIdx.x >> 6;
    int lane = threadIdx.x & 63;
    int cc = scal[1]; if (cc > CANDCAP) cc = CANDCAP;
    int cid = blockIdx.x * 4 + w;
    if (cid >= cc) return;
    int n = candNode[cid];
    int d = (int)stat[n].deg;
    float jac;
    if (d == 0) {
        jac = -INFINITY;
    } else {
        float sum = 0.f;
        if (d <= SLOTS) {
            const int* base = cedge + cid * SLOTS;
            int j;
            int i0, i1, i2, i3; float f0, f1, f2, f3;
            j = lane;       i0 = (j < d) ? base[j] : 0x7fffffff; f0 = (j < d) ? e[i0] : 0.f;
            j = 64 + lane;  i1 = (j < d) ? base[j] : 0x7fffffff; f1 = (j < d) ? e[i1] : 0.f;
            j = 128 + lane; i2 = (j < d) ? base[j] : 0x7fffffff; f2 = (j < d) ? e[i2] : 0.f;
            j = 192 + lane; i3 = (j < d) ? base[j] : 0x7fffffff; f3 = (j < d) ? e[i3] : 0.f;
            int last = -1;
            for (int r = 0; r < d; ++r) {
                int mi = 0x7fffffff; float mv = 0.f;
                if (i0 > last && i0 < mi) { mi = i0; mv = f0; }
                if (i1 > last && i1 < mi) { mi = i1; mv = f1; }
                if (i2 > last && i2 < mi) { mi = i2; mv = f2; }
                if (i3 > last && i3 < mi) { mi = i3; mv = f3; }
#pragma unroll
                for (int s = 32; s >= 1; s >>= 1) {
                    int oi = __shfl_xor(mi, s);
                    float ov = __shfl_xor(mv, s);
                    if (oi < mi) { mi = oi; mv = ov; }
                }
                sum += mv;   // all lanes fold identical values -> identical sum
                last = mi;
            }
        } else {
            // rare fallback (d > 256): ordered ballot scan over all edges
            for (int b0 = 0; b0 < N_EDGES; b0 += 64) {
                int ii = b0 + lane;
                bool m = (ii < N_EDGES) && (dst[ii] == n);
                float v = m ? e[ii] : 0.f;
                unsigned long long bal = __ballot(m);
                while (bal) {
                    int b = __ffsll(bal) - 1;
                    sum += __shfl(v, b);
                    bal &= bal - 1;
                }
            }
        }
        float dd = (float)d;
        float mean = sum / dd;
        float lg = (float)log((double)dd);
        float mx = __uint_as_float(stat[n].mx);   // bitwise-exact max
        jac = (mx - mean) - lg;
    }
    if (lane == 0) {
        out_jacc[n] = jac;
        unsigned int s = __float_as_uint(jac);
        unsigned int asc = (s & 0x80000000u) ? ~s : (s | 0x80000000u);
        candKey[cid] = ((unsigned long long)(~asc) << 32) | (unsigned int)n;
    }
}

__global__ __launch_bounds__(1024) void k_sort(const unsigned long long* __restrict__ candKey,
                                               const int* __restrict__ scal,
                                               float* __restrict__ out_top) {
    __shared__ unsigned long long sk[CANDCAP];
    int t = threadIdx.x;
    int cc = scal[1]; if (cc > CANDCAP) cc = CANDCAP;
    int m = 1024; while (m < cc) m <<= 1;        // cc >= 800 always
    for (int i = t; i < m; i += 1024)
        sk[i] = (i < cc) ? candKey[i] : 0xFFFFFFFFFFFFFFFFULL;
    __syncthreads();
    for (int k = 2; k <= m; k <<= 1) {
        for (int j = k >> 1; j > 0; j >>= 1) {
            for (int i = t; i < m; i += 1024) {
                int ixj = i ^ j;
                if (ixj > i) {
                    unsigned long long a = sk[i], b = sk[ixj];
                    bool up = ((i & k) == 0);
                    if ((a > b) == up) { sk[i] = b; sk[ixj] = a; }
                }
            }
            __syncthreads();
        }
    }
    for (int r = t; r < KSEL; r += 1024)
        out_top[r] = (float)(unsigned int)(sk[r] & 0xFFFFFFFFULL);
}

// fused embed + lap-PE + MLPReadout; weights staged once, 32 nodes per block
__global__ __launch_bounds__(256) void k_mlp(
    const int* __restrict__ tok, const float* __restrict__ pos,
    const float* __restrict__ emb, const float* __restrict__ lapW,
    const float* __restrict__ lapb,
    const float* __restrict__ W0, const float* __restrict__ b0,
    const float* __restrict__ W1, const float* __restrict__ b1,
    const float* __restrict__ W2, const float* __restrict__ b2,
    float* __restrict__ out) {
    __shared__ float sW0[128 * 64];
    __shared__ float sW1[64 * 32];
    __shared__ float sW2[32 * 7];
    __shared__ float sLW[8 * 128];
    __shared__ float sLb[128];
    __shared__ float sb0[64], sb1[32], sb2[7];
    __shared__ float hb[4][128];
    __shared__ float x1[4][64];
    __shared__ float x2[4][32];
    int t = threadIdx.x;
    for (int i = t; i < 128 * 64; i += 256) sW0[i] = W0[i];
    for (int i = t; i < 64 * 32; i += 256) sW1[i] = W1[i];
    for (int i = t; i < 32 * 7; i += 256) sW2[i] = W2[i];
    for (int i = t; i < 8 * 128; i += 256) sLW[i] = lapW[i];
    if (t < 128) sLb[t] = lapb[t];
    if (t < 64) sb0[t] = b0[t];
    if (t < 32) sb1[t] = b1[t];
    if (t < 7) sb2[t] = b2[t];
    __syncthreads();

    int w = t >> 6, l = t & 63;
    int nb = blockIdx.x * 32 + w * 8;            // grid 3125 -> covers 100000 exactly

    for (int it = 0; it < 8; ++it) {
        int node = nb + it;
        int tk = tok[node];
        float p[8];
#pragma unroll
        for (int j = 0; j < 8; ++j) p[j] = pos[node * 8 + j];
#pragma unroll
        for (int c0 = 0; c0 < 128; c0 += 64) {
            int c = c0 + l;
            float acc = sLb[c];
#pragma unroll
            for (int j = 0; j < 8; ++j) acc += p[j] * sLW[j * 128 + c];
            hb[w][c] = emb[tk * 128 + c] + acc;
        }
        __syncthreads();

        float a1 = sb0[l];
        for (int k = 0; k < 128; ++k) a1 += hb[w][k] * sW0[k * 64 + l];
        x1[w][l] = fmaxf(a1, 0.f);
        __syncthreads();

        if (l < 32) {
            float a2 = sb1[l];
            for (int k = 0; k < 64; ++k) a2 += x1[w][k] * sW1[k * 32 + l];
            x2[w][l] = fmaxf(a2, 0.f);
        }
        __syncthreads();

        if (l < 7) {
            float a3 = sb2[l];
            for (int k = 0; k < 32; ++k) a3 += x2[w][k] * sW2[k * 7 + l];
            out[node * 7 + l] = a3;
        }
    }
}

extern "C" void kernel_launch(void* const* d_in, const int* in_sizes, int n_in,
                              void* d_out, int out_size, void* d_ws, size_t ws_size,
                              hipStream_t stream) {
    const int*   h_tokens = (const int*)d_in[0];
    const int*   src      = (const int*)d_in[1];  (void)src;
    const int*   dst      = (const int*)d_in[2];
    const float* e        = (const float*)d_in[3];
    const float* pos      = (const float*)d_in[4];
    const float* emb      = (const float*)d_in[5];
    const float* lapW     = (const float*)d_in[6];
    const float* lapb     = (const float*)d_in[7];
    const float* W0 = (const float*)d_in[8];
    const float* b0 = (const float*)d_in[9];
    const float* W1 = (const float*)d_in[10];
    const float* b1 = (const float*)d_in[11];
    const float* W2 = (const float*)d_in[12];
    const float* b2 = (const float*)d_in[13];
    float* out = (float*)d_out;

    char* ws = (char*)d_ws;
    Stat* stat = (Stat*)(ws + OFF_STAT);
    unsigned int* hist = (unsigned int*)(ws + OFF_HIST);
    int* ccur = (int*)(ws + OFF_CCUR);
    int* scal = (int*)(ws + OFF_SCAL);
    int* candid = (int*)(ws + OFF_CANDID);
    float* rcp = (float*)(ws + OFF_RCP);
    unsigned long long* keys = (unsigned long long*)(ws + OFF_KEYS);
    int* candNode = (int*)(ws + OFF_CANDNODE);
    unsigned long long* candKey = (unsigned long long*)(ws + OFF_CANDKEY);
    int* cedge = (int*)(ws + OFF_CEDGE);

    hipMemsetAsync(ws, 0, ZERO_END, stream);
    hipMemsetAsync(ws + OFF_CANDID, 0xFF, 400000, stream);

    k_stats<<<12500, 256, 0, stream>>>(dst, e, stat);
    k_jacc<<<391, 256, 0, stream>>>(stat, out + OUT_JACC, rcp, keys, hist);
    k_cutoff<<<1, 1024, 0, stream>>>(hist, scal);
    k_collect<<<391, 256, 0, stream>>>(keys, scal, candid, candNode);
    k_gather_score<<<12500, 256, 0, stream>>>(dst, rcp, candid, ccur, cedge,
                                              (float4*)(out + OUT_SCORE));
    k_exact<<<2048, 256, 0, stream>>>(dst, e, stat, candNode, cedge, scal,
                                      out + OUT_JACC, candKey);
    k_sort<<<1, 1024, 0, stream>>>(candKey, scal, out + OUT_TOP);
    k_mlp<<<3125, 256, 0, stream>>>(h_tokens, pos, emb, lapW, lapb,
                                    W0, b0, W1, b1, W2, b2, out);
}

// Round 3
// 557.555 us; speedup vs baseline: 1.8230x; 1.4529x over previous
//
#include <hip/hip_runtime.h>
#include <math.h>

#define N_NODES 100000
#define N_EDGES 3200000
#define KSEL    800
#define CANDCAP 4096
#define SLOTS   256
#define MLPB    1563   // mlp blocks, 64 nodes each  (1563*64 = 100032)
#define STATB   3125   // stats blocks, 1024 edges each (3125*1024 = 3.2M)

// output layout (float offsets)
#define OUT_SCORE 700000
#define OUT_JACC  13500000
#define OUT_TOP   13600000

// ws layout (byte offsets)
#define OFF_CNT      0          // u64[100000]  800000
#define OFF_MX       800000     // u32[100000]  400000
#define OFF_HIST     1200000    // u32[65536]   262144
#define OFF_CCUR     1462144    // int[4096]    16384
#define OFF_SCAL     1478528    // int[64]      256
#define ZERO_END     1478784
#define OFF_CANDID   1478784    // int[100000]  400000  (memset 0xFF)
#define OFF_RCP      1878784    // float[100000]
#define OFF_KEYS     2278784    // u64[100000]
#define OFF_CANDNODE 3078784    // int[4096]
#define OFF_CANDKEY  3095168    // u64[4096]
#define OFF_CEDGE    3127936    // int[4096*256] = 4194304 -> end 7322240

// ---------------- fused stats + MLP ----------------
// grid 4689 x 512: b%3==2 -> mlp block b/3; else stats block (b/3)*2 + b%3
__global__ __launch_bounds__(512) void k_stats_mlp(
    const int* __restrict__ dst, const float* __restrict__ e,
    unsigned long long* __restrict__ cntsum, unsigned int* __restrict__ mx,
    const int* __restrict__ tok, const float* __restrict__ pos,
    const float* __restrict__ emb, const float* __restrict__ lapW,
    const float* __restrict__ lapb,
    const float* __restrict__ W0, const float* __restrict__ b0,
    const float* __restrict__ W1, const float* __restrict__ b1,
    const float* __restrict__ W2, const float* __restrict__ b2,
    float* __restrict__ out) {
    __shared__ float sW0[128 * 64];
    __shared__ float sW1[64 * 32];
    __shared__ float sW2[32 * 7];
    __shared__ float hb[8][128];
    __shared__ float x1[8][64];
    __shared__ float x2[8][32];

    int b = blockIdx.x;
    int t = threadIdx.x;

    if ((b % 3) != 2) {
        // ---- stats: 2 atomics per edge ----
        int sid = (b / 3) * 2 + (b % 3);
        if (sid >= STATB) return;
        long base = (long)sid * 1024 + t * 2;
        int2 d2 = *(const int2*)(dst + base);
        float2 e2 = *(const float2*)(e + base);
        unsigned long long p0 = (1ULL << 52) | (unsigned long long)(e2.x * 67108864.0f);
        unsigned long long p1 = (1ULL << 52) | (unsigned long long)(e2.y * 67108864.0f);
        atomicAdd(&cntsum[d2.x], p0);
        atomicAdd(&cntsum[d2.y], p1);
        atomicMax(&mx[d2.x], __float_as_uint(e2.x));
        atomicMax(&mx[d2.y], __float_as_uint(e2.y));
        return;
    }

    // ---- MLP: 64 nodes per block, 8 waves x 8 nodes ----
    int mb = b / 3;
    for (int i = t; i < 128 * 64; i += 512) sW0[i] = W0[i];
    for (int i = t; i < 64 * 32; i += 512) sW1[i] = W1[i];
    for (int i = t; i < 32 * 7; i += 512) sW2[i] = W2[i];
    __syncthreads();

    int w = t >> 6, l = t & 63;
    int nb = mb * 64 + w * 8;

    for (int it = 0; it < 8; ++it) {
        int node = nb + it;
        bool act = (node < N_NODES);
        if (act) {
            int tk = tok[node];
            float p[8];
#pragma unroll
            for (int j = 0; j < 8; ++j) p[j] = pos[node * 8 + j];
#pragma unroll
            for (int c0 = 0; c0 < 128; c0 += 64) {
                int c = c0 + l;
                float acc = lapb[c];
#pragma unroll
                for (int j = 0; j < 8; ++j) acc += p[j] * lapW[j * 128 + c];
                hb[w][c] = emb[tk * 128 + c] + acc;
            }
        }
        __syncthreads();
        if (act) {
            float a1 = b0[l];
            for (int k = 0; k < 128; ++k) a1 += hb[w][k] * sW0[k * 64 + l];
            x1[w][l] = fmaxf(a1, 0.f);
        }
        __syncthreads();
        if (act && l < 32) {
            float a2 = b1[l];
            for (int k = 0; k < 64; ++k) a2 += x1[w][k] * sW1[k * 32 + l];
            x2[w][l] = fmaxf(a2, 0.f);
        }
        __syncthreads();
        if (act && l < 7) {
            float a3 = b2[l];
            for (int k = 0; k < 32; ++k) a3 += x2[w][k] * sW2[k * 7 + l];
            out[node * 7 + l] = a3;
        }
        __syncthreads();
    }
}

// per node: approx jaccard, rcp, sortable key, 16-bit bucket histogram
__global__ void k_jacc(const unsigned long long* __restrict__ cntsum,
                       const unsigned int* __restrict__ mx,
                       float* __restrict__ out_jacc, float* __restrict__ rcp,
                       unsigned long long* __restrict__ keys,
                       unsigned int* __restrict__ hist) {
    int n = blockIdx.x * 256 + threadIdx.x;
    if (n >= N_NODES) return;
    unsigned long long cs = cntsum[n];
    int d = (int)(cs >> 52);
    float jac, r;
    if (d == 0) {
        jac = -INFINITY;
        r = 1.0f;
    } else {
        float dd = (float)d;
        r = 1.0f / dd;
        float sum = (float)((double)(cs & 0xFFFFFFFFFFFFFULL) * (1.0 / 67108864.0));
        float mean = sum / dd;
        float lg = (float)log((double)dd);
        jac = (__uint_as_float(mx[n]) - mean) - lg;
    }
    out_jacc[n] = jac;
    rcp[n] = r;
    unsigned int s = __float_as_uint(jac);
    unsigned int asc = (s & 0x80000000u) ? ~s : (s | 0x80000000u);
    unsigned int desc = ~asc;
    keys[n] = ((unsigned long long)desc << 32) | (unsigned int)n;
    atomicAdd(&hist[desc >> 16], 1u);
}

__global__ __launch_bounds__(1024) void k_cutoff(const unsigned int* __restrict__ hist,
                                                 int* __restrict__ scal) {
    __shared__ int part[1024];
    int t = threadIdx.x;
    int s = 0;
    for (int b = t * 64; b < t * 64 + 64; ++b) s += (int)hist[b];
    part[t] = s;
    __syncthreads();
    for (int off = 1; off < 1024; off <<= 1) {
        int v = (t >= off) ? part[t - off] : 0;
        __syncthreads();
        part[t] += v;
        __syncthreads();
    }
    int inc = part[t];
    int base = inc - s;
    if (base < KSEL && inc >= KSEL) {
        int run = base;
        for (int b = t * 64; b < t * 64 + 64; ++b) {
            run += (int)hist[b];
            if (run >= KSEL) {
                int cb = b + 1;                 // +1 bucket safety margin
                if (cb > 65535) cb = 65535;
                scal[0] = cb;
                break;
            }
        }
    }
}

__global__ void k_collect(const unsigned long long* __restrict__ keys,
                          int* __restrict__ scal,
                          int* __restrict__ candid, int* __restrict__ candNode) {
    int n = blockIdx.x * 256 + threadIdx.x;
    if (n >= N_NODES) return;
    unsigned int cb = (unsigned int)scal[0];
    if ((unsigned int)(keys[n] >> 48) <= cb) {
        int cid = atomicAdd(&scal[1], 1);
        if (cid < CANDCAP) {
            candid[n] = cid;
            candNode[cid] = n;
        }
    }
}

// write score (1/deg x4) + append candidate edges; 2 edges/thread
__global__ __launch_bounds__(512) void k_gather_score(
    const int* __restrict__ dst, const float* __restrict__ rcp,
    const int* __restrict__ candid,
    int* __restrict__ ccur, int* __restrict__ cedge,
    float4* __restrict__ out_s) {
    long i = ((long)blockIdx.x * 512 + threadIdx.x) * 2;
    int2 d2 = *(const int2*)(dst + i);
    float r0 = rcp[d2.x], r1 = rcp[d2.y];
    out_s[i]     = make_float4(r0, r0, r0, r0);
    out_s[i + 1] = make_float4(r1, r1, r1, r1);
    int c0 = candid[d2.x];
    if (c0 >= 0) {
        int p = atomicAdd(&ccur[c0], 1);
        if (p < SLOTS) cedge[c0 * SLOTS + p] = (int)i;
    }
    int c1 = candid[d2.y];
    if (c1 >= 0) {
        int p = atomicAdd(&ccur[c1], 1);
        if (p < SLOTS) cedge[c1 * SLOTS + p] = (int)i + 1;
    }
}

// exact sequential-order fp32 sum + exact max for candidates (wave per cand)
__global__ __launch_bounds__(256) void k_exact(
    const int* __restrict__ dst, const float* __restrict__ e,
    const unsigned long long* __restrict__ cntsum,
    const int* __restrict__ candNode,
    const int* __restrict__ cedge, const int* __restrict__ scal,
    float* __restrict__ out_jacc, unsigned long long* __restrict__ candKey) {
    int w = threadIdx.x >> 6;
    int lane = threadIdx.x & 63;
    int cc = scal[1]; if (cc > CANDCAP) cc = CANDCAP;
    int cid = blockIdx.x * 4 + w;
    if (cid >= cc) return;
    int n = candNode[cid];
    int d = (int)(cntsum[n] >> 52);
    float jac;
    if (d == 0) {
        jac = -INFINITY;
    } else {
        float sum = 0.f, mxv = -INFINITY;
        if (d <= SLOTS) {
            const int* base = cedge + cid * SLOTS;
            int j;
            int i0, i1, i2, i3; float f0, f1, f2, f3;
            j = lane;       i0 = (j < d) ? base[j] : 0x7fffffff; f0 = (j < d) ? e[i0] : 0.f;
            j = 64 + lane;  i1 = (j < d) ? base[j] : 0x7fffffff; f1 = (j < d) ? e[i1] : 0.f;
            j = 128 + lane; i2 = (j < d) ? base[j] : 0x7fffffff; f2 = (j < d) ? e[i2] : 0.f;
            j = 192 + lane; i3 = (j < d) ? base[j] : 0x7fffffff; f3 = (j < d) ? e[i3] : 0.f;
            int last = -1;
            for (int r = 0; r < d; ++r) {
                int mi = 0x7fffffff; float mv = 0.f;
                if (i0 > last && i0 < mi) { mi = i0; mv = f0; }
                if (i1 > last && i1 < mi) { mi = i1; mv = f1; }
                if (i2 > last && i2 < mi) { mi = i2; mv = f2; }
                if (i3 > last && i3 < mi) { mi = i3; mv = f3; }
#pragma unroll
                for (int s = 32; s >= 1; s >>= 1) {
                    int oi = __shfl_xor(mi, s);
                    float ov = __shfl_xor(mv, s);
                    if (oi < mi) { mi = oi; mv = ov; }
                }
                sum += mv;             // identical fold on all lanes
                mxv = fmaxf(mxv, mv);
                last = mi;
            }
        } else {
            for (int b0 = 0; b0 < N_EDGES; b0 += 64) {
                int ii = b0 + lane;
                bool m = (ii < N_EDGES) && (dst[ii] == n);
                float v = m ? e[ii] : 0.f;
                unsigned long long bal = __ballot(m);
                while (bal) {
                    int bb = __ffsll(bal) - 1;
                    float hv = __shfl(v, bb);
                    sum += hv;
                    mxv = fmaxf(mxv, hv);
                    bal &= bal - 1;
                }
            }
        }
        float dd = (float)d;
        float mean = sum / dd;
        float lg = (float)log((double)dd);
        jac = (mxv - mean) - lg;
    }
    if (lane == 0) {
        out_jacc[n] = jac;
        unsigned int s = __float_as_uint(jac);
        unsigned int asc = (s & 0x80000000u) ? ~s : (s | 0x80000000u);
        candKey[cid] = ((unsigned long long)(~asc) << 32) | (unsigned int)n;
    }
}

__global__ __launch_bounds__(1024) void k_sort(const unsigned long long* __restrict__ candKey,
                                               const int* __restrict__ scal,
                                               float* __restrict__ out_top) {
    __shared__ unsigned long long sk[CANDCAP];
    int t = threadIdx.x;
    int cc = scal[1]; if (cc > CANDCAP) cc = CANDCAP;
    int m = 1024; while (m < cc) m <<= 1;
    for (int i = t; i < m; i += 1024)
        sk[i] = (i < cc) ? candKey[i] : 0xFFFFFFFFFFFFFFFFULL;
    __syncthreads();
    for (int k = 2; k <= m; k <<= 1) {
        for (int j = k >> 1; j > 0; j >>= 1) {
            for (int i = t; i < m; i += 1024) {
                int ixj = i ^ j;
                if (ixj > i) {
                    unsigned long long a = sk[i], bv = sk[ixj];
                    bool up = ((i & k) == 0);
                    if ((a > bv) == up) { sk[i] = bv; sk[ixj] = a; }
                }
            }
            __syncthreads();
        }
    }
    for (int r = t; r < KSEL; r += 1024)
        out_top[r] = (float)(unsigned int)(sk[r] & 0xFFFFFFFFULL);
}

extern "C" void kernel_launch(void* const* d_in, const int* in_sizes, int n_in,
                              void* d_out, int out_size, void* d_ws, size_t ws_size,
                              hipStream_t stream) {
    const int*   h_tokens = (const int*)d_in[0];
    const int*   dst      = (const int*)d_in[2];
    const float* e        = (const float*)d_in[3];
    const float* pos      = (const float*)d_in[4];
    const float* emb      = (const float*)d_in[5];
    const float* lapW     = (const float*)d_in[6];
    const float* lapb     = (const float*)d_in[7];
    const float* W0 = (const float*)d_in[8];
    const float* b0 = (const float*)d_in[9];
    const float* W1 = (const float*)d_in[10];
    const float* b1 = (const float*)d_in[11];
    const float* W2 = (const float*)d_in[12];
    const float* b2 = (const float*)d_in[13];
    float* out = (float*)d_out;

    char* ws = (char*)d_ws;
    unsigned long long* cntsum = (unsigned long long*)(ws + OFF_CNT);
    unsigned int* mx   = (unsigned int*)(ws + OFF_MX);
    unsigned int* hist = (unsigned int*)(ws + OFF_HIST);
    int* ccur = (int*)(ws + OFF_CCUR);
    int* scal = (int*)(ws + OFF_SCAL);
    int* candid = (int*)(ws + OFF_CANDID);
    float* rcp = (float*)(ws + OFF_RCP);
    unsigned long long* keys = (unsigned long long*)(ws + OFF_KEYS);
    int* candNode = (int*)(ws + OFF_CANDNODE);
    unsigned long long* candKey = (unsigned long long*)(ws + OFF_CANDKEY);
    int* cedge = (int*)(ws + OFF_CEDGE);

    hipMemsetAsync(ws, 0, ZERO_END, stream);
    hipMemsetAsync(ws + OFF_CANDID, 0xFF, 400000, stream);

    k_stats_mlp<<<4689, 512, 0, stream>>>(dst, e, cntsum, mx,
                                          h_tokens, pos, emb, lapW, lapb,
                                          W0, b0, W1, b1, W2, b2, out);
    k_jacc<<<391, 256, 0, stream>>>(cntsum, mx, out + OUT_JACC, rcp, keys, hist);
    k_cutoff<<<1, 1024, 0, stream>>>(hist, scal);
    k_collect<<<391, 256, 0, stream>>>(keys, scal, candid, candNode);
    k_gather_score<<<3125, 512, 0, stream>>>(dst, rcp, candid, ccur, cedge,
                                             (float4*)(out + OUT_SCORE));
    k_exact<<<1024, 256, 0, stream>>>(dst, e, cntsum, candNode, cedge, scal,
                                      out + OUT_JACC, candKey);
    k_sort<<<1, 1024, 0, stream>>>(candKey, scal, out + OUT_TOP);
}

// Round 4
// 523.942 us; speedup vs baseline: 1.9400x; 1.0642x over previous
//
#include <hip/hip_runtime.h>
#include <math.h>

#define N_NODES 100000
#define N_EDGES 3200000
#define KSEL    800
#define CANDCAP 4096
#define SLOTS   128
#define NXCD    8
#define STATB   3125   // stats blocks, 1024 edges each

// output layout (float offsets)
#define OUT_SCORE 700000
#define OUT_JACC  13500000
#define OUT_TOP   13600000

// ws layout (byte offsets)
#define OFF_CNT8     0           // u64[8][100000]  6,400,000
#define OFF_MX8      6400000     // u32[8][100000]  3,200,000
#define OFF_HIST     9600000     // u32[65536]      262,144
#define OFF_CCUR     9862144     // int[4096]       16,384
#define OFF_SCAL     9878528     // int[64]         256
#define ZERO_END     9878784
#define OFF_CANDID   9878784     // int[100000]     400,000 (memset 0xFF)
#define OFF_RCP      10278784    // float[100000]
#define OFF_DEG      10678784    // int[100000]
#define OFF_KEYS     11078784    // u64[100000]
#define OFF_CANDNODE 11878784    // int[4096]
#define OFF_CANDKEY  11895168    // u64[4096]
#define OFF_CEDGE    11927936    // int[4096*128] = 2,097,152 -> end 14,025,088

// ---------------- fused stats + MLP ----------------
// grid 4689 x 512: b%3==2 -> mlp block b/3; else stats block (b/3)*2 + b%3
__global__ __launch_bounds__(512) void k_stats_mlp(
    const int* __restrict__ dst, const float* __restrict__ e,
    unsigned long long* __restrict__ cnt8, unsigned int* __restrict__ mx8,
    const int* __restrict__ tok, const float* __restrict__ pos,
    const float* __restrict__ emb, const float* __restrict__ lapW,
    const float* __restrict__ lapb,
    const float* __restrict__ W0, const float* __restrict__ b0,
    const float* __restrict__ W1, const float* __restrict__ b1,
    const float* __restrict__ W2, const float* __restrict__ b2,
    float* __restrict__ out) {
    __shared__ __attribute__((aligned(16))) float sW0[128 * 64];  // interleaved x4
    __shared__ __attribute__((aligned(16))) float sW1[64 * 32];   // interleaved x4
    __shared__ __attribute__((aligned(16))) float sW2[32 * 7];
    __shared__ __attribute__((aligned(16))) float hb[8][128];
    __shared__ __attribute__((aligned(16))) float x1[8][64];
    __shared__ __attribute__((aligned(16))) float x2[8][32];

    int b = blockIdx.x;
    int t = threadIdx.x;

    if ((b % 3) != 2) {
        // ---- stats: XCD-local L2 atomics into per-XCD copy ----
        int sid = (b / 3) * 2 + (b % 3);
        if (sid >= STATB) return;
        unsigned int xcc;
        asm volatile("s_getreg_b32 %0, hwreg(HW_REG_XCC_ID)" : "=s"(xcc));
        xcc &= (NXCD - 1);
        unsigned long long* mycnt = cnt8 + (size_t)xcc * N_NODES;
        unsigned int*       mymx  = mx8  + (size_t)xcc * N_NODES;

        long base = (long)sid * 1024 + t * 2;
        int2 d2 = *(const int2*)(dst + base);
        float2 e2 = *(const float2*)(e + base);
        unsigned long long p0 = (1ULL << 52) | (unsigned long long)(e2.x * 67108864.0f);
        unsigned long long p1 = (1ULL << 52) | (unsigned long long)(e2.y * 67108864.0f);
        __hip_atomic_fetch_add(&mycnt[d2.x], p0, __ATOMIC_RELAXED, __HIP_MEMORY_SCOPE_WORKGROUP);
        __hip_atomic_fetch_add(&mycnt[d2.y], p1, __ATOMIC_RELAXED, __HIP_MEMORY_SCOPE_WORKGROUP);
        __hip_atomic_fetch_max(&mymx[d2.x], __float_as_uint(e2.x), __ATOMIC_RELAXED, __HIP_MEMORY_SCOPE_WORKGROUP);
        __hip_atomic_fetch_max(&mymx[d2.y], __float_as_uint(e2.y), __ATOMIC_RELAXED, __HIP_MEMORY_SCOPE_WORKGROUP);
        return;
    }

    // ---- MLP: 64 nodes per block, 8 waves x 8 nodes ----
    int mb = b / 3;
    for (int i = t; i < 128 * 64; i += 512) {
        int k = i >> 6, l = i & 63;
        sW0[((k >> 2) << 8) + (l << 2) + (k & 3)] = W0[i];
    }
    for (int i = t; i < 64 * 32; i += 512) {
        int k = i >> 5, l = i & 31;
        sW1[((k >> 2) << 7) + (l << 2) + (k & 3)] = W1[i];
    }
    for (int i = t; i < 32 * 7; i += 512) sW2[i] = W2[i];
    __syncthreads();

    int w = t >> 6, l = t & 63;
    int nb = mb * 64 + w * 8;

    for (int it = 0; it < 8; ++it) {
        int node = nb + it;
        bool act = (node < N_NODES);
        if (act) {
            int tk = tok[node];
            float p[8];
#pragma unroll
            for (int j = 0; j < 8; ++j) p[j] = pos[node * 8 + j];
#pragma unroll
            for (int c0 = 0; c0 < 128; c0 += 64) {
                int c = c0 + l;
                float acc = lapb[c];
#pragma unroll
                for (int j = 0; j < 8; ++j) acc += p[j] * lapW[j * 128 + c];
                hb[w][c] = emb[tk * 128 + c] + acc;
            }
        }
        __syncthreads();
        if (act) {
            float a1 = b0[l];
#pragma unroll 8
            for (int kq = 0; kq < 32; ++kq) {
                float4 h4 = *(const float4*)&hb[w][kq << 2];
                float4 w4 = *(const float4*)&sW0[(kq << 8) + (l << 2)];
                a1 += h4.x * w4.x + h4.y * w4.y + h4.z * w4.z + h4.w * w4.w;
            }
            x1[w][l] = fmaxf(a1, 0.f);
        }
        __syncthreads();
        if (act && l < 32) {
            float a2 = b1[l];
#pragma unroll 8
            for (int kq = 0; kq < 16; ++kq) {
                float4 h4 = *(const float4*)&x1[w][kq << 2];
                float4 w4 = *(const float4*)&sW1[(kq << 7) + (l << 2)];
                a2 += h4.x * w4.x + h4.y * w4.y + h4.z * w4.z + h4.w * w4.w;
            }
            x2[w][l] = fmaxf(a2, 0.f);
        }
        __syncthreads();
        if (act && l < 7) {
            float a3 = b2[l];
            for (int k = 0; k < 32; ++k) a3 += x2[w][k] * sW2[k * 7 + l];
            out[node * 7 + l] = a3;
        }
        __syncthreads();
    }
}

// merge 8 XCD copies; approx jaccard, rcp, deg, sortable key, bucket histogram
__global__ void k_jacc(const unsigned long long* __restrict__ cnt8,
                       const unsigned int* __restrict__ mx8,
                       float* __restrict__ out_jacc, float* __restrict__ rcp,
                       int* __restrict__ deg_arr,
                       unsigned long long* __restrict__ keys,
                       unsigned int* __restrict__ hist) {
    int n = blockIdx.x * 256 + threadIdx.x;
    if (n >= N_NODES) return;
    unsigned long long cs = 0;
    unsigned int mxu = 0;
#pragma unroll
    for (int c = 0; c < NXCD; ++c) {
        cs += cnt8[(size_t)c * N_NODES + n];
        unsigned int m = mx8[(size_t)c * N_NODES + n];
        mxu = (m > mxu) ? m : mxu;
    }
    int d = (int)(cs >> 52);
    float jac, r;
    if (d == 0) {
        jac = -INFINITY;
        r = 1.0f;
    } else {
        float dd = (float)d;
        r = 1.0f / dd;
        float sum = (float)((double)(cs & 0xFFFFFFFFFFFFFULL) * (1.0 / 67108864.0));
        float mean = sum / dd;
        float lg = (float)log((double)dd);
        jac = (__uint_as_float(mxu) - mean) - lg;
    }
    out_jacc[n] = jac;
    rcp[n] = r;
    deg_arr[n] = d;
    unsigned int s = __float_as_uint(jac);
    unsigned int asc = (s & 0x80000000u) ? ~s : (s | 0x80000000u);
    unsigned int desc = ~asc;
    keys[n] = ((unsigned long long)desc << 32) | (unsigned int)n;
    atomicAdd(&hist[desc >> 16], 1u);
}

__global__ __launch_bounds__(1024) void k_cutoff(const unsigned int* __restrict__ hist,
                                                 int* __restrict__ scal) {
    __shared__ int part[1024];
    int t = threadIdx.x;
    int s = 0;
    for (int b = t * 64; b < t * 64 + 64; ++b) s += (int)hist[b];
    part[t] = s;
    __syncthreads();
    for (int off = 1; off < 1024; off <<= 1) {
        int v = (t >= off) ? part[t - off] : 0;
        __syncthreads();
        part[t] += v;
        __syncthreads();
    }
    int inc = part[t];
    int base = inc - s;
    if (base < KSEL && inc >= KSEL) {
        int run = base;
        for (int b = t * 64; b < t * 64 + 64; ++b) {
            run += (int)hist[b];
            if (run >= KSEL) {
                int cb = b + 1;                 // +1 bucket safety margin
                if (cb > 65535) cb = 65535;
                scal[0] = cb;
                break;
            }
        }
    }
}

__global__ void k_collect(const unsigned long long* __restrict__ keys,
                          int* __restrict__ scal,
                          int* __restrict__ candid, int* __restrict__ candNode) {
    int n = blockIdx.x * 256 + threadIdx.x;
    if (n >= N_NODES) return;
    unsigned int cb = (unsigned int)scal[0];
    if ((unsigned int)(keys[n] >> 48) <= cb) {
        int cid = atomicAdd(&scal[1], 1);
        if (cid < CANDCAP) {
            candid[n] = cid;
            candNode[cid] = n;
        }
    }
}

// write score (1/deg x4) + append candidate edges; 2 edges/thread
__global__ __launch_bounds__(512) void k_gather_score(
    const int* __restrict__ dst, const float* __restrict__ rcp,
    const int* __restrict__ candid,
    int* __restrict__ ccur, int* __restrict__ cedge,
    float4* __restrict__ out_s) {
    long i = ((long)blockIdx.x * 512 + threadIdx.x) * 2;
    int2 d2 = *(const int2*)(dst + i);
    float r0 = rcp[d2.x], r1 = rcp[d2.y];
    out_s[i]     = make_float4(r0, r0, r0, r0);
    out_s[i + 1] = make_float4(r1, r1, r1, r1);
    int c0 = candid[d2.x];
    if (c0 >= 0) {
        int p = atomicAdd(&ccur[c0], 1);
        if (p < SLOTS) cedge[c0 * SLOTS + p] = (int)i;
    }
    int c1 = candid[d2.y];
    if (c1 >= 0) {
        int p = atomicAdd(&ccur[c1], 1);
        if (p < SLOTS) cedge[c1 * SLOTS + p] = (int)i + 1;
    }
}

// exact sequential-order fp32 sum + exact max for candidates (wave per cand)
__global__ __launch_bounds__(256) void k_exact(
    const int* __restrict__ dst, const float* __restrict__ e,
    const int* __restrict__ deg_arr,
    const int* __restrict__ candNode,
    const int* __restrict__ cedge, const int* __restrict__ scal,
    float* __restrict__ out_jacc, unsigned long long* __restrict__ candKey) {
    int w = threadIdx.x >> 6;
    int lane = threadIdx.x & 63;
    int cc = scal[1]; if (cc > CANDCAP) cc = CANDCAP;
    int cid = blockIdx.x * 4 + w;
    if (cid >= cc) return;
    int n = candNode[cid];
    int d = deg_arr[n];
    float jac;
    if (d == 0) {
        jac = -INFINITY;
    } else {
        float sum = 0.f, mxv = -INFINITY;
        if (d <= SLOTS) {
            const int* base = cedge + cid * SLOTS;
            int j;
            int i0, i1; float f0, f1;
            j = lane;      i0 = (j < d) ? base[j] : 0x7fffffff; f0 = (j < d) ? e[i0] : 0.f;
            j = 64 + lane; i1 = (j < d) ? base[j] : 0x7fffffff; f1 = (j < d) ? e[i1] : 0.f;
            int last = -1;
            for (int r = 0; r < d; ++r) {
                int mi = 0x7fffffff; float mv = 0.f;
                if (i0 > last && i0 < mi) { mi = i0; mv = f0; }
                if (i1 > last && i1 < mi) { mi = i1; mv = f1; }
#pragma unroll
                for (int s = 32; s >= 1; s >>= 1) {
                    int oi = __shfl_xor(mi, s);
                    float ov = __shfl_xor(mv, s);
                    if (oi < mi) { mi = oi; mv = ov; }
                }
                sum += mv;             // identical fold on all lanes
                mxv = fmaxf(mxv, mv);
                last = mi;
            }
        } else {
            for (int b0 = 0; b0 < N_EDGES; b0 += 64) {
                int ii = b0 + lane;
                bool m = (ii < N_EDGES) && (dst[ii] == n);
                float v = m ? e[ii] : 0.f;
                unsigned long long bal = __ballot(m);
                while (bal) {
                    int bb = __ffsll(bal) - 1;
                    float hv = __shfl(v, bb);
                    sum += hv;
                    mxv = fmaxf(mxv, hv);
                    bal &= bal - 1;
                }
            }
        }
        float dd = (float)d;
        float mean = sum / dd;
        float lg = (float)log((double)dd);
        jac = (mxv - mean) - lg;
    }
    if (lane == 0) {
        out_jacc[n] = jac;
        unsigned int s = __float_as_uint(jac);
        unsigned int asc = (s & 0x80000000u) ? ~s : (s | 0x80000000u);
        candKey[cid] = ((unsigned long long)(~asc) << 32) | (unsigned int)n;
    }
}

__global__ __launch_bounds__(1024) void k_sort(const unsigned long long* __restrict__ candKey,
                                               const int* __restrict__ scal,
                                               float* __restrict__ out_top) {
    __shared__ unsigned long long sk[CANDCAP];
    int t = threadIdx.x;
    int cc = scal[1]; if (cc > CANDCAP) cc = CANDCAP;
    int m = 1024; while (m < cc) m <<= 1;
    for (int i = t; i < m; i += 1024)
        sk[i] = (i < cc) ? candKey[i] : 0xFFFFFFFFFFFFFFFFULL;
    __syncthreads();
    for (int k = 2; k <= m; k <<= 1) {
        for (int j = k >> 1; j > 0; j >>= 1) {
            for (int i = t; i < m; i += 1024) {
                int ixj = i ^ j;
                if (ixj > i) {
                    unsigned long long a = sk[i], bv = sk[ixj];
                    bool up = ((i & k) == 0);
                    if ((a > bv) == up) { sk[i] = bv; sk[ixj] = a; }
                }
            }
            __syncthreads();
        }
    }
    for (int r = t; r < KSEL; r += 1024)
        out_top[r] = (float)(unsigned int)(sk[r] & 0xFFFFFFFFULL);
}

extern "C" void kernel_launch(void* const* d_in, const int* in_sizes, int n_in,
                              void* d_out, int out_size, void* d_ws, size_t ws_size,
                              hipStream_t stream) {
    const int*   h_tokens = (const int*)d_in[0];
    const int*   dst      = (const int*)d_in[2];
    const float* e        = (const float*)d_in[3];
    const float* pos      = (const float*)d_in[4];
    const float* emb      = (const float*)d_in[5];
    const float* lapW     = (const float*)d_in[6];
    const float* lapb     = (const float*)d_in[7];
    const float* W0 = (const float*)d_in[8];
    const float* b0 = (const float*)d_in[9];
    const float* W1 = (const float*)d_in[10];
    const float* b1 = (const float*)d_in[11];
    const float* W2 = (const float*)d_in[12];
    const float* b2 = (const float*)d_in[13];
    float* out = (float*)d_out;

    char* ws = (char*)d_ws;
    unsigned long long* cnt8 = (unsigned long long*)(ws + OFF_CNT8);
    unsigned int* mx8  = (unsigned int*)(ws + OFF_MX8);
    unsigned int* hist = (unsigned int*)(ws + OFF_HIST);
    int* ccur = (int*)(ws + OFF_CCUR);
    int* scal = (int*)(ws + OFF_SCAL);
    int* candid = (int*)(ws + OFF_CANDID);
    float* rcp = (float*)(ws + OFF_RCP);
    int* deg_arr = (int*)(ws + OFF_DEG);
    unsigned long long* keys = (unsigned long long*)(ws + OFF_KEYS);
    int* candNode = (int*)(ws + OFF_CANDNODE);
    unsigned long long* candKey = (unsigned long long*)(ws + OFF_CANDKEY);
    int* cedge = (int*)(ws + OFF_CEDGE);

    hipMemsetAsync(ws, 0, ZERO_END, stream);
    hipMemsetAsync(ws + OFF_CANDID, 0xFF, 400000, stream);

    k_stats_mlp<<<4689, 512, 0, stream>>>(dst, e, cnt8, mx8,
                                          h_tokens, pos, emb, lapW, lapb,
                                          W0, b0, W1, b1, W2, b2, out);
    k_jacc<<<391, 256, 0, stream>>>(cnt8, mx8, out + OUT_JACC, rcp, deg_arr,
                                    keys, hist);
    k_cutoff<<<1, 1024, 0, stream>>>(hist, scal);
    k_collect<<<391, 256, 0, stream>>>(keys, scal, candid, candNode);
    k_gather_score<<<3125, 512, 0, stream>>>(dst, rcp, candid, ccur, cedge,
                                             (float4*)(out + OUT_SCORE));
    k_exact<<<1024, 256, 0, stream>>>(dst, e, deg_arr, candNode, cedge, scal,
                                      out + OUT_JACC, candKey);
    k_sort<<<1, 1024, 0, stream>>>(candKey, scal, out + OUT_TOP);
}

// Round 5
// 340.620 us; speedup vs baseline: 2.9840x; 1.5382x over previous
//
#include <hip/hip_runtime.h>
#include <math.h>

#define N_NODES 100000
#define N_EDGES 3200000
#define KSEL    800
#define CANDCAP 4096
#define SLOTS   128
#define NBUCK   196        // node >> 9 -> buckets of 512 nodes
#define BUCKCAP 18432      // avg 16327, +16 sigma
#define PARTB   782        // partition blocks, 4096 edges each

// output layout (float offsets)
#define OUT_SCORE 700000
#define OUT_JACC  13500000
#define OUT_TOP   13600000

// ws layout (byte offsets)
#define OFF_GCUR     0          // u32[256]
#define OFF_HIST     1024       // u32[65536]
#define OFF_CCUR     263168     // int[4096]
#define OFF_SCAL     279552     // int[64]
#define ZERO_END     279808
#define OFF_CANDID   279808     // int[100000] (memset 0xFF)
#define OFF_RCP      679808     // float[100000]
#define OFF_DEG      1079808    // int[100000]
#define OFF_KEYS     1479808    // u64[100000]
#define OFF_CANDNODE 2279808    // int[4096]
#define OFF_CANDKEY  2296192    // u64[4096]
#define OFF_CEDGE    2328960    // int[4096*128]
#define OFF_PART     4426112    // u32[196*18432] -> end 18,876,800

// ---------------- fused: edge partition + MLP-GEMV ----------------
// grid 980 x 512: b%5<4 -> partition sid=(b/5)*4+b%5; b%5==4 -> mlp mid=b/5
__global__ __launch_bounds__(512) void k_part_mlp(
    const int* __restrict__ dst, const float* __restrict__ e,
    unsigned int* __restrict__ gcur, unsigned int* __restrict__ partbuf,
    const int* __restrict__ tok, const float* __restrict__ pos,
    const float* __restrict__ emb, const float* __restrict__ lapW,
    const float* __restrict__ lapb,
    const float* __restrict__ W0, const float* __restrict__ b0,
    const float* __restrict__ W1, const float* __restrict__ b1,
    const float* __restrict__ W2, const float* __restrict__ b2,
    float* __restrict__ out)
{
    __shared__ unsigned int scnt[256], sexc[256], sgb[256], scur[256];
    __shared__ unsigned int sdata[4096];
    __shared__ unsigned char sbuck[4096];

    int b = blockIdx.x;
    int t = threadIdx.x;
    int mode = b % 5;

    if (mode < 4) {
        // ---------- partition: 4096 edges, LDS-staged bucket scatter ----------
        int sid = (b / 5) * 4 + mode;
        if (sid >= PARTB) return;
        long base = (long)sid * 4096;
        int nedge = (int)(N_EDGES - base); if (nedge > 4096) nedge = 4096;
        int myoff = t * 8;
        bool act = myoff < nedge;
        unsigned int pb[8]; unsigned int bb[8];

        if (t < 256) scnt[t] = 0;
        __syncthreads();

        if (act) {
            int4 d4a = *(const int4*)(dst + base + myoff);
            int4 d4b = *(const int4*)(dst + base + myoff + 4);
            float4 e4a = *(const float4*)(e + base + myoff);
            float4 e4b = *(const float4*)(e + base + myoff + 4);
            int dd[8] = {d4a.x, d4a.y, d4a.z, d4a.w, d4b.x, d4b.y, d4b.z, d4b.w};
            float ee[8] = {e4a.x, e4a.y, e4a.z, e4a.w, e4b.x, e4b.y, e4b.z, e4b.w};
#pragma unroll
            for (int j = 0; j < 8; ++j) {
                unsigned int q = (unsigned int)(ee[j] * 65536.0f);
                if (q > 65535u) q = 65535u;
                bb[j] = ((unsigned int)dd[j]) >> 9;
                pb[j] = (q << 9) | ((unsigned int)dd[j] & 511u);
                atomicAdd(&scnt[bb[j]], 1u);
            }
        }
        __syncthreads();

        // exclusive scan over 256 bucket counts
        if (t < 256) sexc[t] = scnt[t];
        __syncthreads();
        for (int off = 1; off < 256; off <<= 1) {
            unsigned int v = 0;
            if (t < 256 && t >= off) v = sexc[t - off];
            __syncthreads();
            if (t < 256) sexc[t] += v;
            __syncthreads();
        }
        if (t < 256) {
            unsigned int c = scnt[t];
            unsigned int ex = sexc[t] - c;
            sexc[t] = ex;
            scur[t] = ex;
            sgb[t] = (c > 0) ? atomicAdd(&gcur[t], c) : 0u;
        }
        __syncthreads();

        if (act) {
#pragma unroll
            for (int j = 0; j < 8; ++j) {
                unsigned int slot = atomicAdd(&scur[bb[j]], 1u);
                sdata[slot] = pb[j];
                sbuck[slot] = (unsigned char)bb[j];
            }
        }
        __syncthreads();

        for (int j = t; j < nedge; j += 512) {
            unsigned int p = sdata[j];
            unsigned int bk = sbuck[j];
            unsigned int gi = sgb[bk] + ((unsigned int)j - sexc[bk]);
            if (gi < BUCKCAP) partbuf[bk * BUCKCAP + gi] = p;
        }
        return;
    }

    // ---------- MLP-GEMV: thread = node; weights via wave-uniform s_load ----------
    int node = (b / 5) * 512 + t;
    if (node >= N_NODES) return;
    int tk = tok[node];
    const float4* pos4 = (const float4*)(pos + (long)node * 8);
    float4 pA = pos4[0], pB = pos4[1];

    float acc[64];
#pragma unroll
    for (int c = 0; c < 64; ++c) acc[c] = b0[c];

    for (int k8 = 0; k8 < 16; ++k8) {
        const float* er = emb + (long)tk * 128 + k8 * 8;
        float4 eA = *(const float4*)(er);
        float4 eB = *(const float4*)(er + 4);
        float ev[8] = {eA.x, eA.y, eA.z, eA.w, eB.x, eB.y, eB.z, eB.w};
        float hh[8];
#pragma unroll
        for (int kk = 0; kk < 8; ++kk) {
            int kidx = k8 * 8 + kk;
            float a = lapb[kidx] + ev[kk];
            a += pA.x * lapW[0 * 128 + kidx];
            a += pA.y * lapW[1 * 128 + kidx];
            a += pA.z * lapW[2 * 128 + kidx];
            a += pA.w * lapW[3 * 128 + kidx];
            a += pB.x * lapW[4 * 128 + kidx];
            a += pB.y * lapW[5 * 128 + kidx];
            a += pB.z * lapW[6 * 128 + kidx];
            a += pB.w * lapW[7 * 128 + kidx];
            hh[kk] = a;
        }
#pragma unroll
        for (int kk = 0; kk < 8; ++kk) {
#pragma unroll
            for (int c = 0; c < 64; ++c)
                acc[c] += hh[kk] * W0[(k8 * 8 + kk) * 64 + c];
        }
    }

    float a2[32];
#pragma unroll
    for (int c = 0; c < 32; ++c) a2[c] = b1[c];
#pragma unroll
    for (int k = 0; k < 64; ++k) {
        float xk = fmaxf(acc[k], 0.f);
#pragma unroll
        for (int c = 0; c < 32; ++c)
            a2[c] += xk * W1[k * 32 + c];
    }

    float a3[7];
#pragma unroll
    for (int c = 0; c < 7; ++c) a3[c] = b2[c];
#pragma unroll
    for (int k = 0; k < 32; ++k) {
        float xk = fmaxf(a2[k], 0.f);
#pragma unroll
        for (int c = 0; c < 7; ++c)
            a3[c] += xk * W2[k * 7 + c];
    }
    float* op = out + (long)node * 7;
#pragma unroll
    for (int c = 0; c < 7; ++c) op[c] = a3[c];
}

// ---------------- per-bucket stats via LDS integer atomics + jacc fold ----------------
__global__ __launch_bounds__(256) void k_bstats(
    const unsigned int* __restrict__ partbuf, const unsigned int* __restrict__ gcur,
    float* __restrict__ out_jacc, float* __restrict__ rcp,
    int* __restrict__ deg_arr, unsigned long long* __restrict__ keys,
    unsigned int* __restrict__ hist)
{
    __shared__ unsigned long long cs[512];   // count<<32 | sumQ16
    __shared__ unsigned int mq[512];         // max of Q16
    int b = blockIdx.x, t = threadIdx.x;
    cs[t] = 0; cs[t + 256] = 0; mq[t] = 0; mq[t + 256] = 0;
    __syncthreads();

    unsigned int cnt = gcur[b]; if (cnt > BUCKCAP) cnt = BUCKCAP;
    const unsigned int* pb = partbuf + b * BUCKCAP;
    for (unsigned int i = t; i < cnt; i += 256) {
        unsigned int p = pb[i];
        unsigned int nl = p & 511u;
        unsigned int q = p >> 9;
        atomicAdd(&cs[nl], (1ULL << 32) | (unsigned long long)q);
        atomicMax(&mq[nl], q);
    }
    __syncthreads();

    for (int tl = t; tl < 512; tl += 256) {
        int node = (b << 9) + tl;
        if (node >= N_NODES) break;
        unsigned long long v = cs[tl];
        int d = (int)(v >> 32);
        float jac, r;
        if (d == 0) {
            jac = -INFINITY; r = 1.0f;
        } else {
            float dd = (float)d;
            r = 1.0f / dd;
            float sum = (float)(unsigned int)(v & 0xFFFFFFFFULL) * (1.0f / 65536.0f);
            float maxf = (float)mq[tl] * (1.0f / 65536.0f);
            float mean = sum / dd;
            float lg = (float)log((double)d);
            jac = (maxf - mean) - lg;
        }
        out_jacc[node] = jac;
        rcp[node] = r;
        deg_arr[node] = d;
        unsigned int s = __float_as_uint(jac);
        unsigned int asc = (s & 0x80000000u) ? ~s : (s | 0x80000000u);
        unsigned int desc = ~asc;
        keys[node] = ((unsigned long long)desc << 32) | (unsigned int)node;
        atomicAdd(&hist[desc >> 16], 1u);
    }
}

__global__ __launch_bounds__(1024) void k_cutoff(const unsigned int* __restrict__ hist,
                                                 int* __restrict__ scal) {
    __shared__ int part[1024];
    int t = threadIdx.x;
    int s = 0;
    for (int b = t * 64; b < t * 64 + 64; ++b) s += (int)hist[b];
    part[t] = s;
    __syncthreads();
    for (int off = 1; off < 1024; off <<= 1) {
        int v = (t >= off) ? part[t - off] : 0;
        __syncthreads();
        part[t] += v;
        __syncthreads();
    }
    int inc = part[t];
    int base = inc - s;
    if (base < KSEL && inc >= KSEL) {
        int run = base;
        for (int b = t * 64; b < t * 64 + 64; ++b) {
            run += (int)hist[b];
            if (run >= KSEL) {
                int cb = b + 1;                 // +1 bucket safety margin
                if (cb > 65535) cb = 65535;
                scal[0] = cb;
                break;
            }
        }
    }
}

__global__ void k_collect(const unsigned long long* __restrict__ keys,
                          int* __restrict__ scal,
                          int* __restrict__ candid, int* __restrict__ candNode) {
    int n = blockIdx.x * 256 + threadIdx.x;
    if (n >= N_NODES) return;
    unsigned int cb = (unsigned int)scal[0];
    if ((unsigned int)(keys[n] >> 48) <= cb) {
        int cid = atomicAdd(&scal[1], 1);
        if (cid < CANDCAP) {
            candid[n] = cid;
            candNode[cid] = n;
        }
    }
}

// write score (1/deg x4) + append candidate edges; 2 edges/thread
__global__ __launch_bounds__(512) void k_gather_score(
    const int* __restrict__ dst, const float* __restrict__ rcp,
    const int* __restrict__ candid,
    int* __restrict__ ccur, int* __restrict__ cedge,
    float4* __restrict__ out_s) {
    long i = ((long)blockIdx.x * 512 + threadIdx.x) * 2;
    int2 d2 = *(const int2*)(dst + i);
    float r0 = rcp[d2.x], r1 = rcp[d2.y];
    out_s[i]     = make_float4(r0, r0, r0, r0);
    out_s[i + 1] = make_float4(r1, r1, r1, r1);
    int c0 = candid[d2.x];
    if (c0 >= 0) {
        int p = atomicAdd(&ccur[c0], 1);
        if (p < SLOTS) cedge[c0 * SLOTS + p] = (int)i;
    }
    int c1 = candid[d2.y];
    if (c1 >= 0) {
        int p = atomicAdd(&ccur[c1], 1);
        if (p < SLOTS) cedge[c1 * SLOTS + p] = (int)i + 1;
    }
}

// exact sequential-order fp32 sum + exact max for candidates (wave per cand)
__global__ __launch_bounds__(256) void k_exact(
    const int* __restrict__ dst, const float* __restrict__ e,
    const int* __restrict__ deg_arr,
    const int* __restrict__ candNode,
    const int* __restrict__ cedge, const int* __restrict__ scal,
    float* __restrict__ out_jacc, unsigned long long* __restrict__ candKey) {
    int w = threadIdx.x >> 6;
    int lane = threadIdx.x & 63;
    int cc = scal[1]; if (cc > CANDCAP) cc = CANDCAP;
    int cid = blockIdx.x * 4 + w;
    if (cid >= cc) return;
    int n = candNode[cid];
    int d = deg_arr[n];
    float jac;
    if (d == 0) {
        jac = -INFINITY;
    } else {
        float sum = 0.f, mxv = -INFINITY;
        if (d <= SLOTS) {
            const int* base = cedge + cid * SLOTS;
            int j;
            int i0, i1; float f0, f1;
            j = lane;      i0 = (j < d) ? base[j] : 0x7fffffff; f0 = (j < d) ? e[i0] : 0.f;
            j = 64 + lane; i1 = (j < d) ? base[j] : 0x7fffffff; f1 = (j < d) ? e[i1] : 0.f;
            int last = -1;
            for (int r = 0; r < d; ++r) {
                int mi = 0x7fffffff; float mv = 0.f;
                if (i0 > last && i0 < mi) { mi = i0; mv = f0; }
                if (i1 > last && i1 < mi) { mi = i1; mv = f1; }
#pragma unroll
                for (int s = 32; s >= 1; s >>= 1) {
                    int oi = __shfl_xor(mi, s);
                    float ov = __shfl_xor(mv, s);
                    if (oi < mi) { mi = oi; mv = ov; }
                }
                sum += mv;             // identical fold on all lanes
                mxv = fmaxf(mxv, mv);
                last = mi;
            }
        } else {
            for (int b0 = 0; b0 < N_EDGES; b0 += 64) {
                int ii = b0 + lane;
                bool m = (ii < N_EDGES) && (dst[ii] == n);
                float v = m ? e[ii] : 0.f;
                unsigned long long bal = __ballot(m);
                while (bal) {
                    int bb = __ffsll(bal) - 1;
                    float hv = __shfl(v, bb);
                    sum += hv;
                    mxv = fmaxf(mxv, hv);
                    bal &= bal - 1;
                }
            }
        }
        float dd = (float)d;
        float mean = sum / dd;
        float lg = (float)log((double)d);
        jac = (mxv - mean) - lg;
    }
    if (lane == 0) {
        out_jacc[n] = jac;
        unsigned int s = __float_as_uint(jac);
        unsigned int asc = (s & 0x80000000u) ? ~s : (s | 0x80000000u);
        candKey[cid] = ((unsigned long long)(~asc) << 32) | (unsigned int)n;
    }
}

__global__ __launch_bounds__(1024) void k_sort(const unsigned long long* __restrict__ candKey,
                                               const int* __restrict__ scal,
                                               float* __restrict__ out_top) {
    __shared__ unsigned long long sk[CANDCAP];
    int t = threadIdx.x;
    int cc = scal[1]; if (cc > CANDCAP) cc = CANDCAP;
    int m = 1024; while (m < cc) m <<= 1;
    for (int i = t; i < m; i += 1024)
        sk[i] = (i < cc) ? candKey[i] : 0xFFFFFFFFFFFFFFFFULL;
    __syncthreads();
    for (int k = 2; k <= m; k <<= 1) {
        for (int j = k >> 1; j > 0; j >>= 1) {
            for (int i = t; i < m; i += 1024) {
                int ixj = i ^ j;
                if (ixj > i) {
                    unsigned long long a = sk[i], bv = sk[ixj];
                    bool up = ((i & k) == 0);
                    if ((a > bv) == up) { sk[i] = bv; sk[ixj] = a; }
                }
            }
            __syncthreads();
        }
    }
    for (int r = t; r < KSEL; r += 1024)
        out_top[r] = (float)(unsigned int)(sk[r] & 0xFFFFFFFFULL);
}

extern "C" void kernel_launch(void* const* d_in, const int* in_sizes, int n_in,
                              void* d_out, int out_size, void* d_ws, size_t ws_size,
                              hipStream_t stream) {
    const int*   h_tokens = (const int*)d_in[0];
    const int*   dst      = (const int*)d_in[2];
    const float* e        = (const float*)d_in[3];
    const float* pos      = (const float*)d_in[4];
    const float* emb      = (const float*)d_in[5];
    const float* lapW     = (const float*)d_in[6];
    const float* lapb     = (const float*)d_in[7];
    const float* W0 = (const float*)d_in[8];
    const float* b0 = (const float*)d_in[9];
    const float* W1 = (const float*)d_in[10];
    const float* b1 = (const float*)d_in[11];
    const float* W2 = (const float*)d_in[12];
    const float* b2 = (const float*)d_in[13];
    float* out = (float*)d_out;

    char* ws = (char*)d_ws;
    unsigned int* gcur = (unsigned int*)(ws + OFF_GCUR);
    unsigned int* hist = (unsigned int*)(ws + OFF_HIST);
    int* ccur = (int*)(ws + OFF_CCUR);
    int* scal = (int*)(ws + OFF_SCAL);
    int* candid = (int*)(ws + OFF_CANDID);
    float* rcp = (float*)(ws + OFF_RCP);
    int* deg_arr = (int*)(ws + OFF_DEG);
    unsigned long long* keys = (unsigned long long*)(ws + OFF_KEYS);
    int* candNode = (int*)(ws + OFF_CANDNODE);
    unsigned long long* candKey = (unsigned long long*)(ws + OFF_CANDKEY);
    int* cedge = (int*)(ws + OFF_CEDGE);
    unsigned int* partbuf = (unsigned int*)(ws + OFF_PART);

    hipMemsetAsync(ws, 0, ZERO_END, stream);
    hipMemsetAsync(ws + OFF_CANDID, 0xFF, 400000, stream);

    k_part_mlp<<<980, 512, 0, stream>>>(dst, e, gcur, partbuf,
                                        h_tokens, pos, emb, lapW, lapb,
                                        W0, b0, W1, b1, W2, b2, out);
    k_bstats<<<NBUCK, 256, 0, stream>>>(partbuf, gcur, out + OUT_JACC, rcp,
                                        deg_arr, keys, hist);
    k_cutoff<<<1, 1024, 0, stream>>>(hist, scal);
    k_collect<<<391, 256, 0, stream>>>(keys, scal, candid, candNode);
    k_gather_score<<<3125, 512, 0, stream>>>(dst, rcp, candid, ccur, cedge,
                                             (float4*)(out + OUT_SCORE));
    k_exact<<<1024, 256, 0, stream>>>(dst, e, deg_arr, candNode, cedge, scal,
                                      out + OUT_JACC, candKey);
    k_sort<<<1, 1024, 0, stream>>>(candKey, scal, out + OUT_TOP);
}

// Round 6
// 340.001 us; speedup vs baseline: 2.9895x; 1.0018x over previous
//
#include <hip/hip_runtime.h>
#include <math.h>

#define N_NODES 100000
#define N_EDGES 3200000
#define KSEL    800
#define CANDCAP 4096
#define SLOTS   128
#define NBUCK   196        // node >> 9 -> buckets of 512 nodes
#define BUCKCAP 18432      // avg 16327, +16 sigma
#define PARTB   782        // partition blocks, 4096 edges each

// output layout (float offsets)
#define OUT_SCORE 700000
#define OUT_JACC  13500000
#define OUT_TOP   13600000

// ws layout (byte offsets)
#define OFF_GCUR     0          // u32[256]
#define OFF_HIST     1024       // u32[65536]
#define OFF_CCUR     263168     // int[4096]
#define OFF_SCAL     279552     // int[64]
#define ZERO_END     279808
#define OFF_CANDID   279808     // int[100000] (memset 0xFF)
#define OFF_RCP      679808     // float[100000]
#define OFF_DEG      1079808    // int[100000]
#define OFF_KEYS     1479808    // u64[100000]
#define OFF_CANDNODE 2279808    // int[4096]
#define OFF_CANDKEY  2296192    // u64[4096]
#define OFF_CEDGE    2328960    // int[4096*128]
#define OFF_PART     4426112    // u32[196*18432] -> end 18,876,800

// ---------------- fused: edge partition + MLP-GEMV ----------------
// grid 980 x 512: b%5<4 -> partition sid=(b/5)*4+b%5; b%5==4 -> mlp mid=b/5
__global__ __launch_bounds__(512) void k_part_mlp(
    const int* __restrict__ dst, const float* __restrict__ e,
    unsigned int* __restrict__ gcur, unsigned int* __restrict__ partbuf,
    const int* __restrict__ tok, const float* __restrict__ pos,
    const float* __restrict__ emb, const float* __restrict__ lapW,
    const float* __restrict__ lapb,
    const float* __restrict__ W0, const float* __restrict__ b0,
    const float* __restrict__ W1, const float* __restrict__ b1,
    const float* __restrict__ W2, const float* __restrict__ b2,
    float* __restrict__ out)
{
    __shared__ unsigned int scnt[256], sexc[256], sgb[256], scur[256];
    __shared__ unsigned int sdata[4096];
    __shared__ unsigned char sbuck[4096];

    int b = blockIdx.x;
    int t = threadIdx.x;
    int mode = b % 5;

    if (mode < 4) {
        // ---------- partition: 4096 edges, LDS-staged bucket scatter ----------
        int sid = (b / 5) * 4 + mode;
        if (sid >= PARTB) return;
        long base = (long)sid * 4096;
        int nedge = (int)(N_EDGES - base); if (nedge > 4096) nedge = 4096;
        int myoff = t * 8;
        bool act = myoff < nedge;
        unsigned int pb[8]; unsigned int bb[8];

        if (t < 256) scnt[t] = 0;
        __syncthreads();

        if (act) {
            int4 d4a = *(const int4*)(dst + base + myoff);
            int4 d4b = *(const int4*)(dst + base + myoff + 4);
            float4 e4a = *(const float4*)(e + base + myoff);
            float4 e4b = *(const float4*)(e + base + myoff + 4);
            int dd[8] = {d4a.x, d4a.y, d4a.z, d4a.w, d4b.x, d4b.y, d4b.z, d4b.w};
            float ee[8] = {e4a.x, e4a.y, e4a.z, e4a.w, e4b.x, e4b.y, e4b.z, e4b.w};
#pragma unroll
            for (int j = 0; j < 8; ++j) {
                unsigned int q = (unsigned int)(ee[j] * 65536.0f);
                if (q > 65535u) q = 65535u;
                bb[j] = ((unsigned int)dd[j]) >> 9;
                pb[j] = (q << 9) | ((unsigned int)dd[j] & 511u);
                atomicAdd(&scnt[bb[j]], 1u);
            }
        }
        __syncthreads();

        // exclusive scan over 256 bucket counts
        if (t < 256) sexc[t] = scnt[t];
        __syncthreads();
        for (int off = 1; off < 256; off <<= 1) {
            unsigned int v = 0;
            if (t < 256 && t >= off) v = sexc[t - off];
            __syncthreads();
            if (t < 256) sexc[t] += v;
            __syncthreads();
        }
        if (t < 256) {
            unsigned int c = scnt[t];
            unsigned int ex = sexc[t] - c;
            sexc[t] = ex;
            scur[t] = ex;
            sgb[t] = (c > 0) ? atomicAdd(&gcur[t], c) : 0u;
        }
        __syncthreads();

        if (act) {
#pragma unroll
            for (int j = 0; j < 8; ++j) {
                unsigned int slot = atomicAdd(&scur[bb[j]], 1u);
                sdata[slot] = pb[j];
                sbuck[slot] = (unsigned char)bb[j];
            }
        }
        __syncthreads();

        for (int j = t; j < nedge; j += 512) {
            unsigned int p = sdata[j];
            unsigned int bk = sbuck[j];
            unsigned int gi = sgb[bk] + ((unsigned int)j - sexc[bk]);
            if (gi < BUCKCAP) partbuf[bk * BUCKCAP + gi] = p;
        }
        return;
    }

    // ---------- MLP-GEMV: thread = node; weights via wave-uniform s_load ----------
    int node = (b / 5) * 512 + t;
    if (node >= N_NODES) return;
    int tk = tok[node];
    const float4* pos4 = (const float4*)(pos + (long)node * 8);
    float4 pA = pos4[0], pB = pos4[1];

    float acc[64];
#pragma unroll
    for (int c = 0; c < 64; ++c) acc[c] = b0[c];

    for (int k8 = 0; k8 < 16; ++k8) {
        const float* er = emb + (long)tk * 128 + k8 * 8;
        float4 eA = *(const float4*)(er);
        float4 eB = *(const float4*)(er + 4);
        float ev[8] = {eA.x, eA.y, eA.z, eA.w, eB.x, eB.y, eB.z, eB.w};
        float hh[8];
#pragma unroll
        for (int kk = 0; kk < 8; ++kk) {
            int kidx = k8 * 8 + kk;
            float a = lapb[kidx] + ev[kk];
            a += pA.x * lapW[0 * 128 + kidx];
            a += pA.y * lapW[1 * 128 + kidx];
            a += pA.z * lapW[2 * 128 + kidx];
            a += pA.w * lapW[3 * 128 + kidx];
            a += pB.x * lapW[4 * 128 + kidx];
            a += pB.y * lapW[5 * 128 + kidx];
            a += pB.z * lapW[6 * 128 + kidx];
            a += pB.w * lapW[7 * 128 + kidx];
            hh[kk] = a;
        }
#pragma unroll
        for (int kk = 0; kk < 8; ++kk) {
#pragma unroll
            for (int c = 0; c < 64; ++c)
                acc[c] += hh[kk] * W0[(k8 * 8 + kk) * 64 + c];
        }
    }

    float a2[32];
#pragma unroll
    for (int c = 0; c < 32; ++c) a2[c] = b1[c];
#pragma unroll
    for (int k = 0; k < 64; ++k) {
        float xk = fmaxf(acc[k], 0.f);
#pragma unroll
        for (int c = 0; c < 32; ++c)
            a2[c] += xk * W1[k * 32 + c];
    }

    float a3[7];
#pragma unroll
    for (int c = 0; c < 7; ++c) a3[c] = b2[c];
#pragma unroll
    for (int k = 0; k < 32; ++k) {
        float xk = fmaxf(a2[k], 0.f);
#pragma unroll
        for (int c = 0; c < 7; ++c)
            a3[c] += xk * W2[k * 7 + c];
    }
    float* op = out + (long)node * 7;
#pragma unroll
    for (int c = 0; c < 7; ++c) op[c] = a3[c];
}

// ---------------- per-bucket stats via NATIVE u32 LDS atomics ----------------
__global__ __launch_bounds__(256) void k_bstats(
    const unsigned int* __restrict__ partbuf, const unsigned int* __restrict__ gcur,
    float* __restrict__ out_jacc, float* __restrict__ rcp,
    int* __restrict__ deg_arr, unsigned long long* __restrict__ keys,
    unsigned int* __restrict__ hist)
{
    __shared__ unsigned int scnt[512];   // count
    __shared__ unsigned int ssum[512];   // sum of Q16 (<= 58*65535 << 2^32)
    __shared__ unsigned int smax[512];   // max of Q16
    int b = blockIdx.x, t = threadIdx.x;
    scnt[t] = 0; scnt[t + 256] = 0;
    ssum[t] = 0; ssum[t + 256] = 0;
    smax[t] = 0; smax[t + 256] = 0;
    __syncthreads();

    unsigned int cnt = gcur[b]; if (cnt > BUCKCAP) cnt = BUCKCAP;
    const unsigned int* pb = partbuf + b * BUCKCAP;
    for (unsigned int i = t; i < cnt; i += 256) {
        unsigned int p = pb[i];
        unsigned int nl = p & 511u;
        unsigned int q = p >> 9;
        atomicAdd(&scnt[nl], 1u);      // native ds_add_u32
        atomicAdd(&ssum[nl], q);       // native ds_add_u32
        atomicMax(&smax[nl], q);       // native ds_max_u32
    }
    __syncthreads();

    for (int tl = t; tl < 512; tl += 256) {
        int node = (b << 9) + tl;
        if (node >= N_NODES) break;
        int d = (int)scnt[tl];
        float jac, r;
        if (d == 0) {
            jac = -INFINITY; r = 1.0f;
        } else {
            float dd = (float)d;
            r = 1.0f / dd;
            float sum = (float)ssum[tl] * (1.0f / 65536.0f);
            float maxf = (float)smax[tl] * (1.0f / 65536.0f);
            float mean = sum / dd;
            float lg = (float)log((double)d);
            jac = (maxf - mean) - lg;
        }
        out_jacc[node] = jac;
        rcp[node] = r;
        deg_arr[node] = d;
        unsigned int s = __float_as_uint(jac);
        unsigned int asc = (s & 0x80000000u) ? ~s : (s | 0x80000000u);
        unsigned int desc = ~asc;
        keys[node] = ((unsigned long long)desc << 32) | (unsigned int)node;
        atomicAdd(&hist[desc >> 16], 1u);
    }
}

__global__ __launch_bounds__(1024) void k_cutoff(const unsigned int* __restrict__ hist,
                                                 int* __restrict__ scal) {
    __shared__ int part[1024];
    int t = threadIdx.x;
    int s = 0;
    for (int b = t * 64; b < t * 64 + 64; ++b) s += (int)hist[b];
    part[t] = s;
    __syncthreads();
    for (int off = 1; off < 1024; off <<= 1) {
        int v = (t >= off) ? part[t - off] : 0;
        __syncthreads();
        part[t] += v;
        __syncthreads();
    }
    int inc = part[t];
    int base = inc - s;
    if (base < KSEL && inc >= KSEL) {
        int run = base;
        for (int b = t * 64; b < t * 64 + 64; ++b) {
            run += (int)hist[b];
            if (run >= KSEL) {
                int cb = b + 1;                 // +1 bucket safety margin
                if (cb > 65535) cb = 65535;
                scal[0] = cb;
                break;
            }
        }
    }
}

__global__ void k_collect(const unsigned long long* __restrict__ keys,
                          int* __restrict__ scal,
                          int* __restrict__ candid, int* __restrict__ candNode) {
    int n = blockIdx.x * 256 + threadIdx.x;
    if (n >= N_NODES) return;
    unsigned int cb = (unsigned int)scal[0];
    if ((unsigned int)(keys[n] >> 48) <= cb) {
        int cid = atomicAdd(&scal[1], 1);
        if (cid < CANDCAP) {
            candid[n] = cid;
            candNode[cid] = n;
        }
    }
}

// write score (1/deg x4) + append candidate edges; 2 edges/thread
__global__ __launch_bounds__(512) void k_gather_score(
    const int* __restrict__ dst, const float* __restrict__ rcp,
    const int* __restrict__ candid,
    int* __restrict__ ccur, int* __restrict__ cedge,
    float4* __restrict__ out_s) {
    long i = ((long)blockIdx.x * 512 + threadIdx.x) * 2;
    int2 d2 = *(const int2*)(dst + i);
    float r0 = rcp[d2.x], r1 = rcp[d2.y];
    out_s[i]     = make_float4(r0, r0, r0, r0);
    out_s[i + 1] = make_float4(r1, r1, r1, r1);
    int c0 = candid[d2.x];
    if (c0 >= 0) {
        int p = atomicAdd(&ccur[c0], 1);
        if (p < SLOTS) cedge[c0 * SLOTS + p] = (int)i;
    }
    int c1 = candid[d2.y];
    if (c1 >= 0) {
        int p = atomicAdd(&ccur[c1], 1);
        if (p < SLOTS) cedge[c1 * SLOTS + p] = (int)i + 1;
    }
}

// exact sequential-order fp32 sum + exact max for candidates (wave per cand)
__global__ __launch_bounds__(256) void k_exact(
    const int* __restrict__ dst, const float* __restrict__ e,
    const int* __restrict__ deg_arr,
    const int* __restrict__ candNode,
    const int* __restrict__ cedge, const int* __restrict__ scal,
    float* __restrict__ out_jacc, unsigned long long* __restrict__ candKey) {
    int w = threadIdx.x >> 6;
    int lane = threadIdx.x & 63;
    int cc = scal[1]; if (cc > CANDCAP) cc = CANDCAP;
    int cid = blockIdx.x * 4 + w;
    if (cid >= cc) return;
    int n = candNode[cid];
    int d = deg_arr[n];
    float jac;
    if (d == 0) {
        jac = -INFINITY;
    } else {
        float sum = 0.f, mxv = -INFINITY;
        if (d <= SLOTS) {
            const int* base = cedge + cid * SLOTS;
            int j;
            int i0, i1; float f0, f1;
            j = lane;      i0 = (j < d) ? base[j] : 0x7fffffff; f0 = (j < d) ? e[i0] : 0.f;
            j = 64 + lane; i1 = (j < d) ? base[j] : 0x7fffffff; f1 = (j < d) ? e[i1] : 0.f;
            int last = -1;
            for (int r = 0; r < d; ++r) {
                int mi = 0x7fffffff; float mv = 0.f;
                if (i0 > last && i0 < mi) { mi = i0; mv = f0; }
                if (i1 > last && i1 < mi) { mi = i1; mv = f1; }
#pragma unroll
                for (int s = 32; s >= 1; s >>= 1) {
                    int oi = __shfl_xor(mi, s);
                    float ov = __shfl_xor(mv, s);
                    if (oi < mi) { mi = oi; mv = ov; }
                }
                sum += mv;             // identical fold on all lanes
                mxv = fmaxf(mxv, mv);
                last = mi;
            }
        } else {
            for (int b0 = 0; b0 < N_EDGES; b0 += 64) {
                int ii = b0 + lane;
                bool m = (ii < N_EDGES) && (dst[ii] == n);
                float v = m ? e[ii] : 0.f;
                unsigned long long bal = __ballot(m);
                while (bal) {
                    int bb = __ffsll(bal) - 1;
                    float hv = __shfl(v, bb);
                    sum += hv;
                    mxv = fmaxf(mxv, hv);
                    bal &= bal - 1;
                }
            }
        }
        float dd = (float)d;
        float mean = sum / dd;
        float lg = (float)log((double)d);
        jac = (mxv - mean) - lg;
    }
    if (lane == 0) {
        out_jacc[n] = jac;
        unsigned int s = __float_as_uint(jac);
        unsigned int asc = (s & 0x80000000u) ? ~s : (s | 0x80000000u);
        candKey[cid] = ((unsigned long long)(~asc) << 32) | (unsigned int)n;
    }
}

__global__ __launch_bounds__(1024) void k_sort(const unsigned long long* __restrict__ candKey,
                                               const int* __restrict__ scal,
                                               float* __restrict__ out_top) {
    __shared__ unsigned long long sk[CANDCAP];
    int t = threadIdx.x;
    int cc = scal[1]; if (cc > CANDCAP) cc = CANDCAP;
    int m = 1024; while (m < cc) m <<= 1;
    for (int i = t; i < m; i += 1024)
        sk[i] = (i < cc) ? candKey[i] : 0xFFFFFFFFFFFFFFFFULL;
    __syncthreads();
    for (int k = 2; k <= m; k <<= 1) {
        for (int j = k >> 1; j > 0; j >>= 1) {
            for (int i = t; i < m; i += 1024) {
                int ixj = i ^ j;
                if (ixj > i) {
                    unsigned long long a = sk[i], bv = sk[ixj];
                    bool up = ((i & k) == 0);
                    if ((a > bv) == up) { sk[i] = bv; sk[ixj] = a; }
                }
            }
            __syncthreads();
        }
    }
    for (int r = t; r < KSEL; r += 1024)
        out_top[r] = (float)(unsigned int)(sk[r] & 0xFFFFFFFFULL);
}

extern "C" void kernel_launch(void* const* d_in, const int* in_sizes, int n_in,
                              void* d_out, int out_size, void* d_ws, size_t ws_size,
                              hipStream_t stream) {
    const int*   h_tokens = (const int*)d_in[0];
    const int*   dst      = (const int*)d_in[2];
    const float* e        = (const float*)d_in[3];
    const float* pos      = (const float*)d_in[4];
    const float* emb      = (const float*)d_in[5];
    const float* lapW     = (const float*)d_in[6];
    const float* lapb     = (const float*)d_in[7];
    const float* W0 = (const float*)d_in[8];
    const float* b0 = (const float*)d_in[9];
    const float* W1 = (const float*)d_in[10];
    const float* b1 = (const float*)d_in[11];
    const float* W2 = (const float*)d_in[12];
    const float* b2 = (const float*)d_in[13];
    float* out = (float*)d_out;

    char* ws = (char*)d_ws;
    unsigned int* gcur = (unsigned int*)(ws + OFF_GCUR);
    unsigned int* hist = (unsigned int*)(ws + OFF_HIST);
    int* ccur = (int*)(ws + OFF_CCUR);
    int* scal = (int*)(ws + OFF_SCAL);
    int* candid = (int*)(ws + OFF_CANDID);
    float* rcp = (float*)(ws + OFF_RCP);
    int* deg_arr = (int*)(ws + OFF_DEG);
    unsigned long long* keys = (unsigned long long*)(ws + OFF_KEYS);
    int* candNode = (int*)(ws + OFF_CANDNODE);
    unsigned long long* candKey = (unsigned long long*)(ws + OFF_CANDKEY);
    int* cedge = (int*)(ws + OFF_CEDGE);
    unsigned int* partbuf = (unsigned int*)(ws + OFF_PART);

    hipMemsetAsync(ws, 0, ZERO_END, stream);
    hipMemsetAsync(ws + OFF_CANDID, 0xFF, 400000, stream);

    k_part_mlp<<<980, 512, 0, stream>>>(dst, e, gcur, partbuf,
                                        h_tokens, pos, emb, lapW, lapb,
                                        W0, b0, W1, b1, W2, b2, out);
    k_bstats<<<NBUCK, 256, 0, stream>>>(partbuf, gcur, out + OUT_JACC, rcp,
                                        deg_arr, keys, hist);
    k_cutoff<<<1, 1024, 0, stream>>>(hist, scal);
    k_collect<<<391, 256, 0, stream>>>(keys, scal, candid, candNode);
    k_gather_score<<<3125, 512, 0, stream>>>(dst, rcp, candid, ccur, cedge,
                                             (float4*)(out + OUT_SCORE));
    k_exact<<<1024, 256, 0, stream>>>(dst, e, deg_arr, candNode, cedge, scal,
                                      out + OUT_JACC, candKey);
    k_sort<<<1, 1024, 0, stream>>>(candKey, scal, out + OUT_TOP);
}

// Round 7
// 203.686 us; speedup vs baseline: 4.9901x; 1.6692x over previous
//
#include <hip/hip_runtime.h>
#include <math.h>

#define N_NODES 100000
#define N_EDGES 3200000
#define KSEL    800
#define CANDCAP 4096
#define SLOTS   128
#define NBUCK   196        // node >> 9 -> buckets of 512 nodes
#define BUCKCAP 18432      // avg 16327, +16 sigma
#define PARTB   782        // partition blocks, 4096 edges each

// output layout (float offsets)
#define OUT_SCORE 700000
#define OUT_JACC  13500000
#define OUT_TOP   13600000

// ws layout (byte offsets)
#define OFF_GCUR     0          // u32[256]
#define OFF_GH1      1024       // u32[2048]  (11-bit prefix histogram)
#define OFF_GH2      9216       // u32[256]   (secondary 8-bit histogram)
#define OFF_CCUR     263168     // int[4096]
#define OFF_SCAL     279552     // int[64]  [0]=thr_u32 [1]=cand cnt [3]=base11 [4]=cb11
#define ZERO_END     279808
#define OFF_CANDID   279808     // int[100000] (memset 0xFF)
#define OFF_RCP      679808     // float[100000]
#define OFF_DEG      1079808    // int[100000]
#define OFF_KEYS     1479808    // u64[100000]
#define OFF_CANDNODE 2279808    // int[4096]
#define OFF_CANDKEY  2296192    // u64[4096]
#define OFF_CEDGE    2328960    // int[4096*128]
#define OFF_PART     4426112    // u32[196*18432] -> end 18,876,800

// ---------------- fused: edge partition + MLP-GEMV ----------------
// grid 980 x 512: b%5<4 -> partition sid=(b/5)*4+b%5; b%5==4 -> mlp mid=b/5
__global__ __launch_bounds__(512) void k_part_mlp(
    const int* __restrict__ dst, const float* __restrict__ e,
    unsigned int* __restrict__ gcur, unsigned int* __restrict__ partbuf,
    const int* __restrict__ tok, const float* __restrict__ pos,
    const float* __restrict__ emb, const float* __restrict__ lapW,
    const float* __restrict__ lapb,
    const float* __restrict__ W0, const float* __restrict__ b0,
    const float* __restrict__ W1, const float* __restrict__ b1,
    const float* __restrict__ W2, const float* __restrict__ b2,
    float* __restrict__ out)
{
    __shared__ unsigned int scnt[256], sexc[256], sgb[256], scur[256];
    __shared__ unsigned int sdata[4096];
    __shared__ unsigned char sbuck[4096];

    int b = blockIdx.x;
    int t = threadIdx.x;
    int mode = b % 5;

    if (mode < 4) {
        // ---------- partition: 4096 edges, LDS-staged bucket scatter ----------
        int sid = (b / 5) * 4 + mode;
        if (sid >= PARTB) return;
        long base = (long)sid * 4096;
        int nedge = (int)(N_EDGES - base); if (nedge > 4096) nedge = 4096;
        int myoff = t * 8;
        bool act = myoff < nedge;
        unsigned int pb[8]; unsigned int bb[8];

        if (t < 256) scnt[t] = 0;
        __syncthreads();

        if (act) {
            int4 d4a = *(const int4*)(dst + base + myoff);
            int4 d4b = *(const int4*)(dst + base + myoff + 4);
            float4 e4a = *(const float4*)(e + base + myoff);
            float4 e4b = *(const float4*)(e + base + myoff + 4);
            int dd[8] = {d4a.x, d4a.y, d4a.z, d4a.w, d4b.x, d4b.y, d4b.z, d4b.w};
            float ee[8] = {e4a.x, e4a.y, e4a.z, e4a.w, e4b.x, e4b.y, e4b.z, e4b.w};
#pragma unroll
            for (int j = 0; j < 8; ++j) {
                unsigned int q = (unsigned int)(ee[j] * 65536.0f);
                if (q > 65535u) q = 65535u;
                bb[j] = ((unsigned int)dd[j]) >> 9;
                pb[j] = (q << 9) | ((unsigned int)dd[j] & 511u);
                atomicAdd(&scnt[bb[j]], 1u);
            }
        }
        __syncthreads();

        // exclusive scan over 256 bucket counts
        if (t < 256) sexc[t] = scnt[t];
        __syncthreads();
        for (int off = 1; off < 256; off <<= 1) {
            unsigned int v = 0;
            if (t < 256 && t >= off) v = sexc[t - off];
            __syncthreads();
            if (t < 256) sexc[t] += v;
            __syncthreads();
        }
        if (t < 256) {
            unsigned int c = scnt[t];
            unsigned int ex = sexc[t] - c;
            sexc[t] = ex;
            scur[t] = ex;
            sgb[t] = (c > 0) ? atomicAdd(&gcur[t], c) : 0u;
        }
        __syncthreads();

        if (act) {
#pragma unroll
            for (int j = 0; j < 8; ++j) {
                unsigned int slot = atomicAdd(&scur[bb[j]], 1u);
                sdata[slot] = pb[j];
                sbuck[slot] = (unsigned char)bb[j];
            }
        }
        __syncthreads();

        for (int j = t; j < nedge; j += 512) {
            unsigned int p = sdata[j];
            unsigned int bk = sbuck[j];
            unsigned int gi = sgb[bk] + ((unsigned int)j - sexc[bk]);
            if (gi < BUCKCAP) partbuf[bk * BUCKCAP + gi] = p;
        }
        return;
    }

    // ---------- MLP-GEMV: thread = node; weights via wave-uniform s_load ----------
    int node = (b / 5) * 512 + t;
    if (node >= N_NODES) return;
    int tk = tok[node];
    const float4* pos4 = (const float4*)(pos + (long)node * 8);
    float4 pA = pos4[0], pB = pos4[1];

    float acc[64];
#pragma unroll
    for (int c = 0; c < 64; ++c) acc[c] = b0[c];

    for (int k8 = 0; k8 < 16; ++k8) {
        const float* er = emb + (long)tk * 128 + k8 * 8;
        float4 eA = *(const float4*)(er);
        float4 eB = *(const float4*)(er + 4);
        float ev[8] = {eA.x, eA.y, eA.z, eA.w, eB.x, eB.y, eB.z, eB.w};
        float hh[8];
#pragma unroll
        for (int kk = 0; kk < 8; ++kk) {
            int kidx = k8 * 8 + kk;
            float a = lapb[kidx] + ev[kk];
            a += pA.x * lapW[0 * 128 + kidx];
            a += pA.y * lapW[1 * 128 + kidx];
            a += pA.z * lapW[2 * 128 + kidx];
            a += pA.w * lapW[3 * 128 + kidx];
            a += pB.x * lapW[4 * 128 + kidx];
            a += pB.y * lapW[5 * 128 + kidx];
            a += pB.z * lapW[6 * 128 + kidx];
            a += pB.w * lapW[7 * 128 + kidx];
            hh[kk] = a;
        }
#pragma unroll
        for (int kk = 0; kk < 8; ++kk) {
#pragma unroll
            for (int c = 0; c < 64; ++c)
                acc[c] += hh[kk] * W0[(k8 * 8 + kk) * 64 + c];
        }
    }

    float a2[32];
#pragma unroll
    for (int c = 0; c < 32; ++c) a2[c] = b1[c];
#pragma unroll
    for (int k = 0; k < 64; ++k) {
        float xk = fmaxf(acc[k], 0.f);
#pragma unroll
        for (int c = 0; c < 32; ++c)
            a2[c] += xk * W1[k * 32 + c];
    }

    float a3[7];
#pragma unroll
    for (int c = 0; c < 7; ++c) a3[c] = b2[c];
#pragma unroll
    for (int k = 0; k < 32; ++k) {
        float xk = fmaxf(a2[k], 0.f);
#pragma unroll
        for (int c = 0; c < 7; ++c)
            a3[c] += xk * W2[k * 7 + c];
    }
    float* op = out + (long)node * 7;
#pragma unroll
    for (int c = 0; c < 7; ++c) op[c] = a3[c];
}

// ---------------- per-bucket stats + PRIVATE 11-bit histogram ----------------
__global__ __launch_bounds__(256) void k_bstats(
    const unsigned int* __restrict__ partbuf, const unsigned int* __restrict__ gcur,
    float* __restrict__ out_jacc, float* __restrict__ rcp,
    int* __restrict__ deg_arr, unsigned long long* __restrict__ keys,
    unsigned int* __restrict__ gh1)
{
    __shared__ unsigned int scnt[512];   // count
    __shared__ unsigned int ssum[512];   // sum of Q16
    __shared__ unsigned int smax[512];   // max of Q16
    __shared__ unsigned int lh1[2048];   // private 11-bit prefix histogram
    int b = blockIdx.x, t = threadIdx.x;
    scnt[t] = 0; scnt[t + 256] = 0;
    ssum[t] = 0; ssum[t + 256] = 0;
    smax[t] = 0; smax[t + 256] = 0;
#pragma unroll
    for (int i = 0; i < 8; ++i) lh1[t + i * 256] = 0;
    __syncthreads();

    unsigned int cnt = gcur[b]; if (cnt > BUCKCAP) cnt = BUCKCAP;
    const unsigned int* pb = partbuf + b * BUCKCAP;
    for (unsigned int i = t; i < cnt; i += 256) {
        unsigned int p = pb[i];
        unsigned int nl = p & 511u;
        unsigned int q = p >> 9;
        atomicAdd(&scnt[nl], 1u);      // native ds_add_u32
        atomicAdd(&ssum[nl], q);       // native ds_add_u32
        atomicMax(&smax[nl], q);       // native ds_max_u32
    }
    __syncthreads();

    for (int tl = t; tl < 512; tl += 256) {
        int node = (b << 9) + tl;
        if (node >= N_NODES) break;
        int d = (int)scnt[tl];
        float jac, r;
        if (d == 0) {
            jac = -INFINITY; r = 1.0f;
        } else {
            float dd = (float)d;
            r = 1.0f / dd;
            float sum = (float)ssum[tl] * (1.0f / 65536.0f);
            float maxf = (float)smax[tl] * (1.0f / 65536.0f);
            float mean = sum / dd;
            float lg = (float)log((double)d);
            jac = (maxf - mean) - lg;
        }
        out_jacc[node] = jac;
        rcp[node] = r;
        deg_arr[node] = d;
        unsigned int s = __float_as_uint(jac);
        unsigned int asc = (s & 0x80000000u) ? ~s : (s | 0x80000000u);
        unsigned int desc = ~asc;
        keys[node] = ((unsigned long long)desc << 32) | (unsigned int)node;
        atomicAdd(&lh1[desc >> 21], 1u);   // LDS, low contention
    }
    __syncthreads();

    // merge non-empty bins only (~15/block)
#pragma unroll
    for (int i = 0; i < 8; ++i) {
        unsigned int c = lh1[t + i * 256];
        if (c) atomicAdd(&gh1[t + i * 256], c);
    }
}

// find 11-bit cutoff bucket cb11 and base rank (nodes strictly above window)
__global__ __launch_bounds__(256) void k_cut1(const unsigned int* __restrict__ gh1,
                                              int* __restrict__ scal) {
    __shared__ unsigned int part[256];
    int t = threadIdx.x;
    unsigned int s = 0;
    for (int b = t * 8; b < t * 8 + 8; ++b) s += gh1[b];
    part[t] = s;
    __syncthreads();
    for (int off = 1; off < 256; off <<= 1) {
        unsigned int v = (t >= off) ? part[t - off] : 0;
        __syncthreads();
        part[t] += v;
        __syncthreads();
    }
    unsigned int inc = part[t];
    unsigned int base = inc - s;
    if (base < KSEL && inc >= KSEL) {
        unsigned int run = base;
        for (int b = t * 8; b < t * 8 + 8; ++b) {
            unsigned int h = gh1[b];
            if (run + h >= KSEL) {
                scal[4] = b;          // cb11
                scal[3] = (int)run;   // base11
                break;
            }
            run += h;
        }
    }
}

// secondary histogram: bits [13:21) of desc, window nodes only, privatized
__global__ __launch_bounds__(1024) void k_hist2(const unsigned long long* __restrict__ keys,
                                                const int* __restrict__ scal,
                                                unsigned int* __restrict__ gh2) {
    __shared__ unsigned int lh[256];
    int t = threadIdx.x;
    if (t < 256) lh[t] = 0;
    __syncthreads();
    int n = blockIdx.x * 1024 + t;
    unsigned int cb11 = (unsigned int)scal[4];
    if (n < N_NODES) {
        unsigned int desc = (unsigned int)(keys[n] >> 32);
        if ((desc >> 21) == cb11)
            atomicAdd(&lh[(desc >> 13) & 255u], 1u);
    }
    __syncthreads();
    if (t < 256 && lh[t]) atomicAdd(&gh2[t], lh[t]);
}

// final threshold: include through bucket cb8+1 (one-bucket drift margin)
__global__ __launch_bounds__(256) void k_cut2(const unsigned int* __restrict__ gh2,
                                              int* __restrict__ scal) {
    __shared__ unsigned int h[256];
    int t = threadIdx.x;
    h[t] = gh2[t];
    __syncthreads();
    if (t == 0) {
        unsigned int run = (unsigned int)scal[3];
        unsigned int cb8 = 255;
        for (int b = 0; b < 256; ++b) {
            run += h[b];
            if (run >= KSEL) { cb8 = (unsigned int)b; break; }
        }
        unsigned long long thr = ((unsigned long long)(unsigned int)scal[4] << 21)
                               + (((unsigned long long)cb8 + 2ULL) << 13);
        if (thr > 0x100000000ULL) thr = 0x100000000ULL;
        scal[0] = (int)(unsigned int)(thr - 1ULL);   // inclusive threshold on desc
    }
}

// collect candidates: block-aggregated reservation (1 global atomic per block)
__global__ __launch_bounds__(1024) void k_collect(
    const unsigned long long* __restrict__ keys,
    int* __restrict__ scal,
    int* __restrict__ candid, int* __restrict__ candNode) {
    __shared__ unsigned int wcnt[16], wbase[16], bbase;
    int t = threadIdx.x;
    int wv = t >> 6, lane = t & 63;
    int n = blockIdx.x * 1024 + t;
    unsigned int thr = (unsigned int)scal[0];
    bool isc = false;
    if (n < N_NODES) {
        unsigned int desc = (unsigned int)(keys[n] >> 32);
        isc = (desc <= thr);
    }
    unsigned long long bal = __ballot(isc);
    if (lane == 0) wcnt[wv] = (unsigned int)__popcll(bal);
    __syncthreads();
    if (t == 0) {
        unsigned int s = 0;
        for (int i = 0; i < 16; ++i) { wbase[i] = s; s += wcnt[i]; }
        bbase = s ? (unsigned int)atomicAdd(&scal[1], (int)s) : 0u;
    }
    __syncthreads();
    if (isc) {
        unsigned int pos = bbase + wbase[wv]
                         + (unsigned int)__popcll(bal & ((1ULL << lane) - 1ULL));
        if (pos < CANDCAP) {
            candid[n] = (int)pos;
            candNode[pos] = n;
        }
    }
}

// write score (1/deg x4) + append candidate edges; 2 edges/thread
__global__ __launch_bounds__(512) void k_gather_score(
    const int* __restrict__ dst, const float* __restrict__ rcp,
    const int* __restrict__ candid,
    int* __restrict__ ccur, int* __restrict__ cedge,
    float4* __restrict__ out_s) {
    long i = ((long)blockIdx.x * 512 + threadIdx.x) * 2;
    int2 d2 = *(const int2*)(dst + i);
    float r0 = rcp[d2.x], r1 = rcp[d2.y];
    out_s[i]     = make_float4(r0, r0, r0, r0);
    out_s[i + 1] = make_float4(r1, r1, r1, r1);
    int c0 = candid[d2.x];
    if (c0 >= 0) {
        int p = atomicAdd(&ccur[c0], 1);
        if (p < SLOTS) cedge[c0 * SLOTS + p] = (int)i;
    }
    int c1 = candid[d2.y];
    if (c1 >= 0) {
        int p = atomicAdd(&ccur[c1], 1);
        if (p < SLOTS) cedge[c1 * SLOTS + p] = (int)i + 1;
    }
}

// exact sequential-order fp32 sum + exact max for candidates (wave per cand)
__global__ __launch_bounds__(256) void k_exact(
    const int* __restrict__ dst, const float* __restrict__ e,
    const int* __restrict__ deg_arr,
    const int* __restrict__ candNode,
    const int* __restrict__ cedge, const int* __restrict__ scal,
    float* __restrict__ out_jacc, unsigned long long* __restrict__ candKey) {
    int w = threadIdx.x >> 6;
    int lane = threadIdx.x & 63;
    int cc = scal[1]; if (cc > CANDCAP) cc = CANDCAP;
    int cid = blockIdx.x * 4 + w;
    if (cid >= cc) return;
    int n = candNode[cid];
    int d = deg_arr[n];
    float jac;
    if (d == 0) {
        jac = -INFINITY;
    } else {
        float sum = 0.f, mxv = -INFINITY;
        if (d <= SLOTS) {
            const int* base = cedge + cid * SLOTS;
            int j;
            int i0, i1; float f0, f1;
            j = lane;      i0 = (j < d) ? base[j] : 0x7fffffff; f0 = (j < d) ? e[i0] : 0.f;
            j = 64 + lane; i1 = (j < d) ? base[j] : 0x7fffffff; f1 = (j < d) ? e[i1] : 0.f;
            int last = -1;
            for (int r = 0; r < d; ++r) {
                int mi = 0x7fffffff; float mv = 0.f;
                if (i0 > last && i0 < mi) { mi = i0; mv = f0; }
                if (i1 > last && i1 < mi) { mi = i1; mv = f1; }
#pragma unroll
                for (int s = 32; s >= 1; s >>= 1) {
                    int oi = __shfl_xor(mi, s);
                    float ov = __shfl_xor(mv, s);
                    if (oi < mi) { mi = oi; mv = ov; }
                }
                sum += mv;             // identical fold on all lanes
                mxv = fmaxf(mxv, mv);
                last = mi;
            }
        } else {
            for (int b0 = 0; b0 < N_EDGES; b0 += 64) {
                int ii = b0 + lane;
                bool m = (ii < N_EDGES) && (dst[ii] == n);
                float v = m ? e[ii] : 0.f;
                unsigned long long bal = __ballot(m);
                while (bal) {
                    int bb = __ffsll(bal) - 1;
                    float hv = __shfl(v, bb);
                    sum += hv;
                    mxv = fmaxf(mxv, hv);
                    bal &= bal - 1;
                }
            }
        }
        float dd = (float)d;
        float mean = sum / dd;
        float lg = (float)log((double)d);
        jac = (mxv - mean) - lg;
    }
    if (lane == 0) {
        out_jacc[n] = jac;
        unsigned int s = __float_as_uint(jac);
        unsigned int asc = (s & 0x80000000u) ? ~s : (s | 0x80000000u);
        candKey[cid] = ((unsigned long long)(~asc) << 32) | (unsigned int)n;
    }
}

__global__ __launch_bounds__(1024) void k_sort(const unsigned long long* __restrict__ candKey,
                                               const int* __restrict__ scal,
                                               float* __restrict__ out_top) {
    __shared__ unsigned long long sk[CANDCAP];
    int t = threadIdx.x;
    int cc = scal[1]; if (cc > CANDCAP) cc = CANDCAP;
    int m = 1024; while (m < cc) m <<= 1;
    for (int i = t; i < m; i += 1024)
        sk[i] = (i < cc) ? candKey[i] : 0xFFFFFFFFFFFFFFFFULL;
    __syncthreads();
    for (int k = 2; k <= m; k <<= 1) {
        for (int j = k >> 1; j > 0; j >>= 1) {
            for (int i = t; i < m; i += 1024) {
                int ixj = i ^ j;
                if (ixj > i) {
                    unsigned long long a = sk[i], bv = sk[ixj];
                    bool up = ((i & k) == 0);
                    if ((a > bv) == up) { sk[i] = bv; sk[ixj] = a; }
                }
            }
            __syncthreads();
        }
    }
    for (int r = t; r < KSEL; r += 1024)
        out_top[r] = (float)(unsigned int)(sk[r] & 0xFFFFFFFFULL);
}

extern "C" void kernel_launch(void* const* d_in, const int* in_sizes, int n_in,
                              void* d_out, int out_size, void* d_ws, size_t ws_size,
                              hipStream_t stream) {
    const int*   h_tokens = (const int*)d_in[0];
    const int*   dst      = (const int*)d_in[2];
    const float* e        = (const float*)d_in[3];
    const float* pos      = (const float*)d_in[4];
    const float* emb      = (const float*)d_in[5];
    const float* lapW     = (const float*)d_in[6];
    const float* lapb     = (const float*)d_in[7];
    const float* W0 = (const float*)d_in[8];
    const float* b0 = (const float*)d_in[9];
    const float* W1 = (const float*)d_in[10];
    const float* b1 = (const float*)d_in[11];
    const float* W2 = (const float*)d_in[12];
    const float* b2 = (const float*)d_in[13];
    float* out = (float*)d_out;

    char* ws = (char*)d_ws;
    unsigned int* gcur = (unsigned int*)(ws + OFF_GCUR);
    unsigned int* gh1  = (unsigned int*)(ws + OFF_GH1);
    unsigned int* gh2  = (unsigned int*)(ws + OFF_GH2);
    int* ccur = (int*)(ws + OFF_CCUR);
    int* scal = (int*)(ws + OFF_SCAL);
    int* candid = (int*)(ws + OFF_CANDID);
    float* rcp = (float*)(ws + OFF_RCP);
    int* deg_arr = (int*)(ws + OFF_DEG);
    unsigned long long* keys = (unsigned long long*)(ws + OFF_KEYS);
    int* candNode = (int*)(ws + OFF_CANDNODE);
    unsigned long long* candKey = (unsigned long long*)(ws + OFF_CANDKEY);
    int* cedge = (int*)(ws + OFF_CEDGE);
    unsigned int* partbuf = (unsigned int*)(ws + OFF_PART);

    hipMemsetAsync(ws, 0, ZERO_END, stream);
    hipMemsetAsync(ws + OFF_CANDID, 0xFF, 400000, stream);

    k_part_mlp<<<980, 512, 0, stream>>>(dst, e, gcur, partbuf,
                                        h_tokens, pos, emb, lapW, lapb,
                                        W0, b0, W1, b1, W2, b2, out);
    k_bstats<<<NBUCK, 256, 0, stream>>>(partbuf, gcur, out + OUT_JACC, rcp,
                                        deg_arr, keys, gh1);
    k_cut1<<<1, 256, 0, stream>>>(gh1, scal);
    k_hist2<<<98, 1024, 0, stream>>>(keys, scal, gh2);
    k_cut2<<<1, 256, 0, stream>>>(gh2, scal);
    k_collect<<<98, 1024, 0, stream>>>(keys, scal, candid, candNode);
    k_gather_score<<<3125, 512, 0, stream>>>(dst, rcp, candid, ccur, cedge,
                                             (float4*)(out + OUT_SCORE));
    k_exact<<<1024, 256, 0, stream>>>(dst, e, deg_arr, candNode, cedge, scal,
                                      out + OUT_JACC, candKey);
    k_sort<<<1, 1024, 0, stream>>>(candKey, scal, out + OUT_TOP);
}

// Round 8
// 193.312 us; speedup vs baseline: 5.2580x; 1.0537x over previous
//
#include <hip/hip_runtime.h>
#include <math.h>

#define N_NODES 100000
#define N_EDGES 3200000
#define KSEL    800
#define CANDCAP 4096
#define SLOTS   128
#define NBUCK   196        // node >> 9 -> buckets of 512 nodes
#define BUCKCAP 18432      // avg 16327, +16 sigma
#define EPB     8192
#define PARTB   391        // partition blocks, 8192 edges each (391*8192 >= 3.2M)

// output layout (float offsets)
#define OUT_SCORE 700000
#define OUT_JACC  13500000
#define OUT_TOP   13600000

// ws layout (byte offsets)
#define OFF_GCUR     0          // u32[256]
#define OFF_GH1      1024       // u32[2048]  (11-bit prefix histogram)
#define OFF_GH2      9216       // u32[256]   (secondary 8-bit histogram)
#define OFF_CCUR     263168     // int[4096]
#define OFF_SCAL     279552     // int[64]  [1]=cand cnt
#define ZERO_END     279808
#define OFF_CANDID   279808     // int[100000] (memset 0xFF)
#define OFF_RCP      679808     // float[100000]
#define OFF_DEG      1079808    // int[100000]
#define OFF_KEYS     1479808    // u64[100000]
#define OFF_CANDNODE 2279808    // int[4096]
#define OFF_CANDKEY  2296192    // u64[4096]
#define OFF_CEDGE    2328960    // int[4096*128]
#define OFF_PART     4426112    // u32[196*18432] -> end 18,876,800

// ---------------- fused: edge partition + MLP-GEMV ----------------
// grid 588 x 512: b%3<2 -> partition sid=(b/3)*2+b%3; b%3==2 -> mlp mid=b/3
__global__ __launch_bounds__(512, 2) void k_part_mlp(
    const int* __restrict__ dst, const float* __restrict__ e,
    unsigned int* __restrict__ gcur, unsigned int* __restrict__ partbuf,
    const int* __restrict__ tok, const float* __restrict__ pos,
    const float* __restrict__ emb, const float* __restrict__ lapW,
    const float* __restrict__ lapb,
    const float* __restrict__ W0, const float* __restrict__ b0,
    const float* __restrict__ W1, const float* __restrict__ b1,
    const float* __restrict__ W2, const float* __restrict__ b2,
    float* __restrict__ out)
{
    __shared__ unsigned int scnt[256], sexc[256], sgb[256], scur[256];
    __shared__ unsigned int sdata[EPB];
    __shared__ unsigned char sbuck[EPB];

    int b = blockIdx.x;
    int t = threadIdx.x;
    int mode = b % 3;

    if (mode < 2) {
        // ---------- partition: 8192 edges, LDS-staged bucket scatter ----------
        int sid = (b / 3) * 2 + mode;
        if (sid >= PARTB) return;
        long base = (long)sid * EPB;
        int nedge = (int)(N_EDGES - base); if (nedge > EPB) nedge = EPB;
        int myoff = t * 16;
        bool act = myoff < nedge;
        unsigned int pb[16]; unsigned int bb[16];

        if (t < 256) scnt[t] = 0;
        __syncthreads();

        if (act) {
#pragma unroll
            for (int g = 0; g < 4; ++g) {
                int4 d4 = *(const int4*)(dst + base + myoff + g * 4);
                float4 e4 = *(const float4*)(e + base + myoff + g * 4);
                int dd[4] = {d4.x, d4.y, d4.z, d4.w};
                float ee[4] = {e4.x, e4.y, e4.z, e4.w};
#pragma unroll
                for (int j = 0; j < 4; ++j) {
                    unsigned int q = (unsigned int)(ee[j] * 65536.0f);
                    if (q > 65535u) q = 65535u;
                    int idx = g * 4 + j;
                    bb[idx] = ((unsigned int)dd[j]) >> 9;
                    pb[idx] = (q << 9) | ((unsigned int)dd[j] & 511u);
                    atomicAdd(&scnt[bb[idx]], 1u);
                }
            }
        }
        __syncthreads();

        // single-wave exclusive scan over 256 bucket counts (no barriers inside)
        if (t < 64) {
            unsigned int c0 = scnt[t * 4], c1 = scnt[t * 4 + 1];
            unsigned int c2 = scnt[t * 4 + 2], c3 = scnt[t * 4 + 3];
            unsigned int p0 = c0, p1 = p0 + c1, p2 = p1 + c2, p3 = p2 + c3;
            unsigned int run = p3;
#pragma unroll
            for (int off = 1; off < 64; off <<= 1) {
                unsigned int v = __shfl_up(run, off);
                if (t >= off) run += v;
            }
            unsigned int exc = run - p3;
            sexc[t * 4]     = exc;
            sexc[t * 4 + 1] = exc + p0;
            sexc[t * 4 + 2] = exc + p1;
            sexc[t * 4 + 3] = exc + p2;
        }
        __syncthreads();
        if (t < 256) {
            unsigned int c = scnt[t];
            scur[t] = sexc[t];
            sgb[t] = (c > 0) ? atomicAdd(&gcur[t], c) : 0u;
        }
        __syncthreads();

        if (act) {
#pragma unroll
            for (int j = 0; j < 16; ++j) {
                unsigned int slot = atomicAdd(&scur[bb[j]], 1u);
                sdata[slot] = pb[j];
                sbuck[slot] = (unsigned char)bb[j];
            }
        }
        __syncthreads();

        for (int j = t; j < nedge; j += 512) {
            unsigned int p = sdata[j];
            unsigned int bk = sbuck[j];
            unsigned int gi = sgb[bk] + ((unsigned int)j - sexc[bk]);
            if (gi < BUCKCAP) partbuf[bk * BUCKCAP + gi] = p;
        }
        return;
    }

    // ---------- MLP-GEMV: thread = node; weights via wave-uniform s_load ----------
    int node = (b / 3) * 512 + t;
    if (node >= N_NODES) return;
    int tk = tok[node];
    const float4* pos4 = (const float4*)(pos + (long)node * 8);
    float4 pA = pos4[0], pB = pos4[1];

    float acc[64];
#pragma unroll
    for (int c = 0; c < 64; ++c) acc[c] = b0[c];

    for (int k8 = 0; k8 < 16; ++k8) {
        const float* er = emb + (long)tk * 128 + k8 * 8;
        float4 eA = *(const float4*)(er);
        float4 eB = *(const float4*)(er + 4);
        float ev[8] = {eA.x, eA.y, eA.z, eA.w, eB.x, eB.y, eB.z, eB.w};
        float hh[8];
#pragma unroll
        for (int kk = 0; kk < 8; ++kk) {
            int kidx = k8 * 8 + kk;
            float a = lapb[kidx] + ev[kk];
            a += pA.x * lapW[0 * 128 + kidx];
            a += pA.y * lapW[1 * 128 + kidx];
            a += pA.z * lapW[2 * 128 + kidx];
            a += pA.w * lapW[3 * 128 + kidx];
            a += pB.x * lapW[4 * 128 + kidx];
            a += pB.y * lapW[5 * 128 + kidx];
            a += pB.z * lapW[6 * 128 + kidx];
            a += pB.w * lapW[7 * 128 + kidx];
            hh[kk] = a;
        }
#pragma unroll
        for (int kk = 0; kk < 8; ++kk) {
#pragma unroll
            for (int c = 0; c < 64; ++c)
                acc[c] += hh[kk] * W0[(k8 * 8 + kk) * 64 + c];
        }
    }

    float a2[32];
#pragma unroll
    for (int c = 0; c < 32; ++c) a2[c] = b1[c];
#pragma unroll
    for (int k = 0; k < 64; ++k) {
        float xk = fmaxf(acc[k], 0.f);
#pragma unroll
        for (int c = 0; c < 32; ++c)
            a2[c] += xk * W1[k * 32 + c];
    }

    float a3[7];
#pragma unroll
    for (int c = 0; c < 7; ++c) a3[c] = b2[c];
#pragma unroll
    for (int k = 0; k < 32; ++k) {
        float xk = fmaxf(a2[k], 0.f);
#pragma unroll
        for (int c = 0; c < 7; ++c)
            a3[c] += xk * W2[k * 7 + c];
    }
    float* op = out + (long)node * 7;
#pragma unroll
    for (int c = 0; c < 7; ++c) op[c] = a3[c];
}

// ---------------- per-bucket stats + PRIVATE 11-bit histogram ----------------
__global__ __launch_bounds__(256) void k_bstats(
    const unsigned int* __restrict__ partbuf, const unsigned int* __restrict__ gcur,
    float* __restrict__ out_jacc, float* __restrict__ rcp,
    int* __restrict__ deg_arr, unsigned long long* __restrict__ keys,
    unsigned int* __restrict__ gh1)
{
    __shared__ unsigned int scnt[512];
    __shared__ unsigned int ssum[512];
    __shared__ unsigned int smax[512];
    __shared__ unsigned int lh1[2048];
    int b = blockIdx.x, t = threadIdx.x;
    scnt[t] = 0; scnt[t + 256] = 0;
    ssum[t] = 0; ssum[t + 256] = 0;
    smax[t] = 0; smax[t + 256] = 0;
#pragma unroll
    for (int i = 0; i < 8; ++i) lh1[t + i * 256] = 0;
    __syncthreads();

    unsigned int cnt = gcur[b]; if (cnt > BUCKCAP) cnt = BUCKCAP;
    const unsigned int* pb = partbuf + b * BUCKCAP;
    for (unsigned int i = t; i < cnt; i += 256) {
        unsigned int p = pb[i];
        unsigned int nl = p & 511u;
        unsigned int q = p >> 9;
        atomicAdd(&scnt[nl], 1u);
        atomicAdd(&ssum[nl], q);
        atomicMax(&smax[nl], q);
    }
    __syncthreads();

    for (int tl = t; tl < 512; tl += 256) {
        int node = (b << 9) + tl;
        if (node >= N_NODES) break;
        int d = (int)scnt[tl];
        float jac, r;
        if (d == 0) {
            jac = -INFINITY; r = 1.0f;
        } else {
            float dd = (float)d;
            r = 1.0f / dd;
            float sum = (float)ssum[tl] * (1.0f / 65536.0f);
            float maxf = (float)smax[tl] * (1.0f / 65536.0f);
            float mean = sum / dd;
            float lg = (float)log((double)d);
            jac = (maxf - mean) - lg;
        }
        out_jacc[node] = jac;
        rcp[node] = r;
        deg_arr[node] = d;
        unsigned int s = __float_as_uint(jac);
        unsigned int asc = (s & 0x80000000u) ? ~s : (s | 0x80000000u);
        unsigned int desc = ~asc;
        keys[node] = ((unsigned long long)desc << 32) | (unsigned int)node;
        atomicAdd(&lh1[desc >> 21], 1u);
    }
    __syncthreads();

#pragma unroll
    for (int i = 0; i < 8; ++i) {
        unsigned int c = lh1[t + i * 256];
        if (c) atomicAdd(&gh1[t + i * 256], c);
    }
}

// derive (cb11, base11) from gh1 — block-local helper (all threads participate)
__device__ __forceinline__ void derive_cut1(const unsigned int* gh1,
                                            unsigned int* part,   // [256] LDS
                                            unsigned int* res,    // [2] LDS
                                            int t) {
    unsigned int s = 0;
    if (t < 256) {
        for (int b8 = t * 8; b8 < t * 8 + 8; ++b8) s += gh1[b8];
        part[t] = s;
    }
    __syncthreads();
    for (int off = 1; off < 256; off <<= 1) {
        unsigned int v = 0;
        if (t < 256 && t >= off) v = part[t - off];
        __syncthreads();
        if (t < 256) part[t] += v;
        __syncthreads();
    }
    if (t < 256) {
        unsigned int inc = part[t];
        unsigned int base = inc - s;
        if (base < KSEL && inc >= KSEL) {
            unsigned int run = base;
            for (int b8 = t * 8; b8 < t * 8 + 8; ++b8) {
                unsigned int h = gh1[b8];
                if (run + h >= KSEL) { res[0] = (unsigned int)b8; res[1] = run; break; }
                run += h;
            }
        }
    }
    __syncthreads();
}

// secondary histogram of bits [13:21) over window nodes (cut1 derived in-block)
__global__ __launch_bounds__(1024) void k_hist2(const unsigned long long* __restrict__ keys,
                                                const unsigned int* __restrict__ gh1,
                                                unsigned int* __restrict__ gh2) {
    __shared__ unsigned int part[256];
    __shared__ unsigned int res[2];
    __shared__ unsigned int lh[256];
    int t = threadIdx.x;
    if (t < 256) lh[t] = 0;
    derive_cut1(gh1, part, res, t);
    unsigned int cb11 = res[0];
    int n = blockIdx.x * 1024 + t;
    if (n < N_NODES) {
        unsigned int desc = (unsigned int)(keys[n] >> 32);
        if ((desc >> 21) == cb11)
            atomicAdd(&lh[(desc >> 13) & 255u], 1u);
    }
    __syncthreads();
    if (t < 256 && lh[t]) atomicAdd(&gh2[t], lh[t]);
}

// collect candidates (cut1+cut2 derived in-block; 1 global atomic per block)
__global__ __launch_bounds__(1024) void k_collect(
    const unsigned long long* __restrict__ keys,
    const unsigned int* __restrict__ gh1, const unsigned int* __restrict__ gh2,
    int* __restrict__ scal,
    int* __restrict__ candid, int* __restrict__ candNode) {
    __shared__ unsigned int part[256];
    __shared__ unsigned int res[2];
    __shared__ unsigned int h2[256];
    __shared__ unsigned int thr_s;
    __shared__ unsigned int wcnt[16], wbase[16], bbase;
    int t = threadIdx.x;
    if (t < 256) h2[t] = gh2[t];
    derive_cut1(gh1, part, res, t);
    if (t == 0) {
        unsigned int run = res[1];
        unsigned int cb8 = 255;
        for (int b8 = 0; b8 < 256; ++b8) {
            run += h2[b8];
            if (run >= KSEL) { cb8 = (unsigned int)b8; break; }
        }
        unsigned long long thr = ((unsigned long long)res[0] << 21)
                               + (((unsigned long long)cb8 + 2ULL) << 13);
        if (thr > 0x100000000ULL) thr = 0x100000000ULL;
        thr_s = (unsigned int)(thr - 1ULL);
    }
    __syncthreads();

    int wv = t >> 6, lane = t & 63;
    int n = blockIdx.x * 1024 + t;
    unsigned int thr = thr_s;
    bool isc = false;
    if (n < N_NODES) {
        unsigned int desc = (unsigned int)(keys[n] >> 32);
        isc = (desc <= thr);
    }
    unsigned long long bal = __ballot(isc);
    if (lane == 0) wcnt[wv] = (unsigned int)__popcll(bal);
    __syncthreads();
    if (t == 0) {
        unsigned int s = 0;
        for (int i = 0; i < 16; ++i) { wbase[i] = s; s += wcnt[i]; }
        bbase = s ? (unsigned int)atomicAdd(&scal[1], (int)s) : 0u;
    }
    __syncthreads();
    if (isc) {
        unsigned int pos = bbase + wbase[wv]
                         + (unsigned int)__popcll(bal & ((1ULL << lane) - 1ULL));
        if (pos < CANDCAP) {
            candid[n] = (int)pos;
            candNode[pos] = n;
        }
    }
}

// write score (1/deg x4) + append candidate edges; 2 edges/thread
__global__ __launch_bounds__(512) void k_gather_score(
    const int* __restrict__ dst, const float* __restrict__ rcp,
    const int* __restrict__ candid,
    int* __restrict__ ccur, int* __restrict__ cedge,
    float4* __restrict__ out_s) {
    long i = ((long)blockIdx.x * 512 + threadIdx.x) * 2;
    int2 d2 = *(const int2*)(dst + i);
    float r0 = rcp[d2.x], r1 = rcp[d2.y];
    out_s[i]     = make_float4(r0, r0, r0, r0);
    out_s[i + 1] = make_float4(r1, r1, r1, r1);
    int c0 = candid[d2.x];
    if (c0 >= 0) {
        int p = atomicAdd(&ccur[c0], 1);
        if (p < SLOTS) cedge[c0 * SLOTS + p] = (int)i;
    }
    int c1 = candid[d2.y];
    if (c1 >= 0) {
        int p = atomicAdd(&ccur[c1], 1);
        if (p < SLOTS) cedge[c1 * SLOTS + p] = (int)i + 1;
    }
}

// exact sequential-order fp32 sum + exact max for candidates (wave per cand)
__global__ __launch_bounds__(256) void k_exact(
    const int* __restrict__ dst, const float* __restrict__ e,
    const int* __restrict__ deg_arr,
    const int* __restrict__ candNode,
    const int* __restrict__ cedge, const int* __restrict__ scal,
    float* __restrict__ out_jacc, unsigned long long* __restrict__ candKey) {
    int w = threadIdx.x >> 6;
    int lane = threadIdx.x & 63;
    int cc = scal[1]; if (cc > CANDCAP) cc = CANDCAP;
    int cid = blockIdx.x * 4 + w;
    if (cid >= cc) return;
    int n = candNode[cid];
    int d = deg_arr[n];
    float jac;
    if (d == 0) {
        jac = -INFINITY;
    } else {
        float sum = 0.f, mxv = -INFINITY;
        if (d <= SLOTS) {
            const int* base = cedge + cid * SLOTS;
            int j;
            int i0, i1; float f0, f1;
            j = lane;      i0 = (j < d) ? base[j] : 0x7fffffff; f0 = (j < d) ? e[i0] : 0.f;
            j = 64 + lane; i1 = (j < d) ? base[j] : 0x7fffffff; f1 = (j < d) ? e[i1] : 0.f;
            int last = -1;
            for (int r = 0; r < d; ++r) {
                int mi = 0x7fffffff; float mv = 0.f;
                if (i0 > last && i0 < mi) { mi = i0; mv = f0; }
                if (i1 > last && i1 < mi) { mi = i1; mv = f1; }
#pragma unroll
                for (int s = 32; s >= 1; s >>= 1) {
                    int oi = __shfl_xor(mi, s);
                    float ov = __shfl_xor(mv, s);
                    if (oi < mi) { mi = oi; mv = ov; }
                }
                sum += mv;
                mxv = fmaxf(mxv, mv);
                last = mi;
            }
        } else {
            for (int b0 = 0; b0 < N_EDGES; b0 += 64) {
                int ii = b0 + lane;
                bool m = (ii < N_EDGES) && (dst[ii] == n);
                float v = m ? e[ii] : 0.f;
                unsigned long long bal = __ballot(m);
                while (bal) {
                    int bb = __ffsll(bal) - 1;
                    float hv = __shfl(v, bb);
                    sum += hv;
                    mxv = fmaxf(mxv, hv);
                    bal &= bal - 1;
                }
            }
        }
        float dd = (float)d;
        float mean = sum / dd;
        float lg = (float)log((double)d);
        jac = (mxv - mean) - lg;
    }
    if (lane == 0) {
        out_jacc[n] = jac;
        unsigned int s = __float_as_uint(jac);
        unsigned int asc = (s & 0x80000000u) ? ~s : (s | 0x80000000u);
        candKey[cid] = ((unsigned long long)(~asc) << 32) | (unsigned int)n;
    }
}

__global__ __launch_bounds__(1024) void k_sort(const unsigned long long* __restrict__ candKey,
                                               const int* __restrict__ scal,
                                               float* __restrict__ out_top) {
    __shared__ unsigned long long sk[CANDCAP];
    int t = threadIdx.x;
    int cc = scal[1]; if (cc > CANDCAP) cc = CANDCAP;
    int m = 1024; while (m < cc) m <<= 1;
    for (int i = t; i < m; i += 1024)
        sk[i] = (i < cc) ? candKey[i] : 0xFFFFFFFFFFFFFFFFULL;
    __syncthreads();
    for (int k = 2; k <= m; k <<= 1) {
        for (int j = k >> 1; j > 0; j >>= 1) {
            for (int i = t; i < m; i += 1024) {
                int ixj = i ^ j;
                if (ixj > i) {
                    unsigned long long a = sk[i], bv = sk[ixj];
                    bool up = ((i & k) == 0);
                    if ((a > bv) == up) { sk[i] = bv; sk[ixj] = a; }
                }
            }
            __syncthreads();
        }
    }
    for (int r = t; r < KSEL; r += 1024)
        out_top[r] = (float)(unsigned int)(sk[r] & 0xFFFFFFFFULL);
}

extern "C" void kernel_launch(void* const* d_in, const int* in_sizes, int n_in,
                              void* d_out, int out_size, void* d_ws, size_t ws_size,
                              hipStream_t stream) {
    const int*   h_tokens = (const int*)d_in[0];
    const int*   dst      = (const int*)d_in[2];
    const float* e        = (const float*)d_in[3];
    const float* pos      = (const float*)d_in[4];
    const float* emb      = (const float*)d_in[5];
    const float* lapW     = (const float*)d_in[6];
    const float* lapb     = (const float*)d_in[7];
    const float* W0 = (const float*)d_in[8];
    const float* b0 = (const float*)d_in[9];
    const float* W1 = (const float*)d_in[10];
    const float* b1 = (const float*)d_in[11];
    const float* W2 = (const float*)d_in[12];
    const float* b2 = (const float*)d_in[13];
    float* out = (float*)d_out;

    char* ws = (char*)d_ws;
    unsigned int* gcur = (unsigned int*)(ws + OFF_GCUR);
    unsigned int* gh1  = (unsigned int*)(ws + OFF_GH1);
    unsigned int* gh2  = (unsigned int*)(ws + OFF_GH2);
    int* ccur = (int*)(ws + OFF_CCUR);
    int* scal = (int*)(ws + OFF_SCAL);
    int* candid = (int*)(ws + OFF_CANDID);
    float* rcp = (float*)(ws + OFF_RCP);
    int* deg_arr = (int*)(ws + OFF_DEG);
    unsigned long long* keys = (unsigned long long*)(ws + OFF_KEYS);
    int* candNode = (int*)(ws + OFF_CANDNODE);
    unsigned long long* candKey = (unsigned long long*)(ws + OFF_CANDKEY);
    int* cedge = (int*)(ws + OFF_CEDGE);
    unsigned int* partbuf = (unsigned int*)(ws + OFF_PART);

    hipMemsetAsync(ws, 0, ZERO_END, stream);
    hipMemsetAsync(ws + OFF_CANDID, 0xFF, 400000, stream);

    k_part_mlp<<<588, 512, 0, stream>>>(dst, e, gcur, partbuf,
                                        h_tokens, pos, emb, lapW, lapb,
                                        W0, b0, W1, b1, W2, b2, out);
    k_bstats<<<NBUCK, 256, 0, stream>>>(partbuf, gcur, out + OUT_JACC, rcp,
                                        deg_arr, keys, gh1);
    k_hist2<<<98, 1024, 0, stream>>>(keys, gh1, gh2);
    k_collect<<<98, 1024, 0, stream>>>(keys, gh1, gh2, scal, candid, candNode);
    k_gather_score<<<3125, 512, 0, stream>>>(dst, rcp, candid, ccur, cedge,
                                             (float4*)(out + OUT_SCORE));
    k_exact<<<1024, 256, 0, stream>>>(dst, e, deg_arr, candNode, cedge, scal,
                                      out + OUT_JACC, candKey);
    k_sort<<<1, 1024, 0, stream>>>(candKey, scal, out + OUT_TOP);
}